// Round 1
// baseline (2479.048 us; speedup 1.0000x reference)
//
#include <hip/hip_runtime.h>
#include <cstddef>
#include <cstdint>

// Problem constants (fixed by setup_inputs)
#define E_EDGES 131072
#define N_NODES 8192
#define D_INF   192
#define L_DIM   256
#define NW_DIM  160
#define M_CH    32
#define OUT_D   416
#define QK_DIM  512
#define CHUNK   32768
#define EPS6    1e-6f

// ws layout (float offsets)
#define WS_H    0ull
#define WS_ATT  33554432ull                    // E*256
#define WS_NMAX (WS_ATT + 4194304ull)          // E*32
#define WS_NSUM (WS_NMAX + 262144ull)          // N*32
#define WS_ENV  (WS_NSUM + 262144ull)          // N*32
#define WS_ENV2 (WS_ENV + 1048576ull)          // N*128

// ---------------- generic tiled f32 GEMM: C = act(A@W + bias) ----------------
// A: (rows,K) lda, W: (K,N) ldw=N, C: (rows,N) ldc. rows multiple of 64.
template<int ACT>
__global__ __launch_bounds__(256) void gemm_kernel(
    const float* __restrict__ A, int lda,
    const float* __restrict__ W, int ldw,
    const float* __restrict__ bias,
    float* __restrict__ C, int ldc,
    int Ncols, int Kdim)
{
  __shared__ float As[16][65];
  __shared__ float Ws[16][64];
  const int tid = threadIdx.x;
  const int row0 = blockIdx.y * 64;
  const int n0 = blockIdx.x * 64;
  const int tx = tid & 15, ty = tid >> 4;
  const int ar = tid >> 2, ak = (tid & 3) << 2;
  const int wr = tid >> 4, wc = (tid & 15) << 2;
  float acc[4][4] = {};
  for (int k0 = 0; k0 < Kdim; k0 += 16) {
    float4 av = *(const float4*)(A + (size_t)(row0 + ar) * lda + k0 + ak);
    As[ak+0][ar]=av.x; As[ak+1][ar]=av.y; As[ak+2][ar]=av.z; As[ak+3][ar]=av.w;
    int wn = n0 + wc;
    const float* wp = W + (size_t)(k0 + wr) * ldw + wn;
    float4 wv;
    if (wn + 3 < Ncols) wv = *(const float4*)wp;
    else {
      wv.x = (wn+0<Ncols)?wp[0]:0.f; wv.y=(wn+1<Ncols)?wp[1]:0.f;
      wv.z = (wn+2<Ncols)?wp[2]:0.f; wv.w=(wn+3<Ncols)?wp[3]:0.f;
    }
    Ws[wr][wc+0]=wv.x; Ws[wr][wc+1]=wv.y; Ws[wr][wc+2]=wv.z; Ws[wr][wc+3]=wv.w;
    __syncthreads();
    #pragma unroll
    for (int kk = 0; kk < 16; ++kk) {
      float a[4], b[4];
      #pragma unroll
      for (int i=0;i<4;++i) a[i] = As[kk][ty*4+i];
      #pragma unroll
      for (int j=0;j<4;++j) b[j] = Ws[kk][tx*4+j];
      #pragma unroll
      for (int i=0;i<4;++i)
        #pragma unroll
        for (int j=0;j<4;++j) acc[i][j] += a[i]*b[j];
    }
    __syncthreads();
  }
  #pragma unroll
  for (int i=0;i<4;++i) {
    int r = row0 + ty*4 + i;
    #pragma unroll
    for (int j=0;j<4;++j) {
      int n = n0 + tx*4 + j;
      if (n < Ncols) {
        float v = acc[i][j];
        if (bias) v += bias[n];
        if (ACT == 1) v = v / (1.f + __expf(-v));   // silu
        C[(size_t)r*ldc + n] = v;
      }
    }
  }
}

// ---------------- Q GEMM with efa gather: efa=[ninv[ctr],ninv[nbr],einv] ----
// K=192 fixed, N=512 fixed, C: (CHUNK,512)
__global__ __launch_bounds__(256) void gemm_efa_kernel(
    const float* __restrict__ node_inv,
    const float* __restrict__ edge_inv,
    const int* __restrict__ ctr,
    const int* __restrict__ nbr,
    int e0,
    const float* __restrict__ W,
    float* __restrict__ C)
{
  __shared__ float As[16][65];
  __shared__ float Ws[16][64];
  const int tid = threadIdx.x;
  const int row0 = blockIdx.y * 64;
  const int n0 = blockIdx.x * 64;
  const int tx = tid & 15, ty = tid >> 4;
  const int ar = tid >> 2, ak = (tid & 3) << 2;
  const int wr = tid >> 4, wc = (tid & 15) << 2;
  const int ge = e0 + row0 + ar;
  const int c_idx = ctr[ge], n_idx = nbr[ge];
  float acc[4][4] = {};
  for (int k0 = 0; k0 < 192; k0 += 16) {
    int k = k0 + ak;
    const float* src;
    if (k < 64)       src = node_inv + (size_t)c_idx*64 + k;
    else if (k < 128) src = node_inv + (size_t)n_idx*64 + (k-64);
    else              src = edge_inv + (size_t)ge*64 + (k-128);
    float4 av = *(const float4*)src;
    As[ak+0][ar]=av.x; As[ak+1][ar]=av.y; As[ak+2][ar]=av.z; As[ak+3][ar]=av.w;
    float4 wv = *(const float4*)(W + (size_t)(k0 + wr) * 512 + n0 + wc);
    Ws[wr][wc+0]=wv.x; Ws[wr][wc+1]=wv.y; Ws[wr][wc+2]=wv.z; Ws[wr][wc+3]=wv.w;
    __syncthreads();
    #pragma unroll
    for (int kk = 0; kk < 16; ++kk) {
      float a[4], b[4];
      #pragma unroll
      for (int i=0;i<4;++i) a[i] = As[kk][ty*4+i];
      #pragma unroll
      for (int j=0;j<4;++j) b[j] = Ws[kk][tx*4+j];
      #pragma unroll
      for (int i=0;i<4;++i)
        #pragma unroll
        for (int j=0;j<4;++j) acc[i][j] += a[i]*b[j];
    }
    __syncthreads();
  }
  #pragma unroll
  for (int i=0;i<4;++i)
    #pragma unroll
    for (int j=0;j<4;++j)
      C[(size_t)(row0 + ty*4 + i)*512 + n0 + tx*4 + j] = acc[i][j];
}

// ---------------- LayerNorm + cutoff on d_out cols 0..255, in place --------
__global__ __launch_bounds__(256) void ln_cutoff_kernel(
    float* __restrict__ out, const float* __restrict__ g,
    const float* __restrict__ b, const float* __restrict__ cut)
{
  __shared__ float2 red[256];
  const int e = blockIdx.x, t = threadIdx.x;
  float v = out[(size_t)e*OUT_D + t];
  red[t] = make_float2(v, v*v);
  __syncthreads();
  for (int off=128; off>0; off>>=1) {
    if (t < off) { red[t].x += red[t+off].x; red[t].y += red[t+off].y; }
    __syncthreads();
  }
  float mean = red[0].x * (1.f/256.f);
  float var  = red[0].y * (1.f/256.f) - mean*mean;
  float nv = (v - mean) * rsqrtf(var + 1e-5f) * g[t] + b[t];
  if (t < 128) nv *= cut[e];
  out[(size_t)e*OUT_D + t] = nv;
}

// ---------------- QK dot: logits[e,m] = 4 * sum_d Q*K -----------------------
__global__ __launch_bounds__(256) void qk_dot_kernel(
    const float* __restrict__ Q, const float* __restrict__ K,
    float* __restrict__ att, int e0)
{
  const int tid = blockIdx.x * 256 + threadIdx.x;
  const int le = tid >> 5, m = tid & 31;
  const float* q = Q + (size_t)le*QK_DIM + m*16;
  const float* k = K + (size_t)le*QK_DIM + m*16;
  float s = 0.f;
  #pragma unroll
  for (int d=0; d<16; d+=4) {
    float4 qv = *(const float4*)(q+d);
    float4 kv = *(const float4*)(k+d);
    s += qv.x*kv.x + qv.y*kv.y + qv.z*kv.z + qv.w*kv.w;
  }
  att[(size_t)(e0+le)*32 + m] = 4.0f * s;
}

// ---------------- scatter softmax helpers -----------------------------------
__device__ __forceinline__ unsigned fenc(float x){
  unsigned u = __float_as_uint(x);
  return (u & 0x80000000u) ? ~u : (u | 0x80000000u);
}
__device__ __forceinline__ float fdec(unsigned k){
  return (k & 0x80000000u) ? __uint_as_float(k & 0x7fffffffu) : __uint_as_float(~k);
}

__global__ __launch_bounds__(256) void seg_max_kernel(
    const float* __restrict__ att, const int* __restrict__ ctr,
    unsigned* __restrict__ nmax)
{
  const int tid = blockIdx.x*256 + threadIdx.x;
  const int e = tid >> 5, m = tid & 31;
  atomicMax(&nmax[(size_t)ctr[e]*32 + m], fenc(att[tid]));
}

__global__ __launch_bounds__(256) void seg_expsum_kernel(
    float* __restrict__ att, const int* __restrict__ ctr,
    const unsigned* __restrict__ nmax, float* __restrict__ nsum)
{
  const int tid = blockIdx.x*256 + threadIdx.x;
  const int e = tid >> 5, m = tid & 31;
  const size_t ci = (size_t)ctr[e]*32 + m;
  float ex = __expf(att[tid] - fdec(nmax[ci]));
  att[tid] = ex;
  atomicAdd(&nsum[ci], ex);
}

// ---------------- env accumulation (emb * att scattered to nodes) -----------
__global__ __launch_bounds__(256) void env_accum_kernel(
    const float* __restrict__ att, const int* __restrict__ ctr,
    const float* __restrict__ nsum, const float* __restrict__ edge_attr,
    const float* __restrict__ outbuf, float* __restrict__ env)
{
  const int tid = blockIdx.x*256 + threadIdx.x;
  const int e = tid >> 5, m = tid & 31;
  const size_t ci = (size_t)ctr[e]*32 + m;
  float a = att[tid] / (nsum[ci] + 1e-16f);
  const float* wr = outbuf + (size_t)e*OUT_D + 256;   // weights row
  float w0 = wr[64 + 2*m], w1 = wr[65 + 2*m], sc = wr[128 + m];
  float4 ea = *(const float4*)(edge_attr + ((size_t)e*32 + m)*4);
  float cs = sc * a;
  float* dst = env + ci*4;
  atomicAdd(dst+0, ea.x*w0*cs);
  atomicAdd(dst+1, ea.y*w1*cs);
  atomicAdd(dst+2, ea.z*w1*cs);
  atomicAdd(dst+3, ea.w*w1*cs);
}

// ---------------- env so3_norm + channel mixing ------------------------------
__global__ __launch_bounds__(128) void env_post_kernel(
    const float* __restrict__ env, const float* __restrict__ env_norm_w,
    const float* __restrict__ env_lin_w, float* __restrict__ env2)
{
  __shared__ float ev[128];
  __shared__ float2 red[128];
  const int n = blockIdx.x, t = threadIdx.x;
  const int d = t & 3, k = t >> 2;
  float val = env[(size_t)n*128 + t];
  red[t] = make_float2(d==0 ? val*val : 0.f, d!=0 ? val*val : 0.f);
  __syncthreads();
  for (int off=64; off>0; off>>=1) {
    if (t<off){ red[t].x += red[t+off].x; red[t].y += red[t+off].y; }
    __syncthreads();
  }
  float inv_s = rsqrtf(red[0].x*(1.f/32.f)+EPS6);
  float inv_v = rsqrtf(red[0].y*(1.f/96.f)+EPS6);
  float nv = (d==0) ? val*inv_s*env_norm_w[2*k] : val*inv_v*env_norm_w[2*k+1];
  ev[t] = nv;
  __syncthreads();
  const float* WL = env_lin_w + (d==0 ? 0 : 1024);
  float acc = 0.f;
  #pragma unroll 8
  for (int m=0;m<32;++m) acc += ev[m*4+d]*WL[m*32+k];
  env2[(size_t)n*128 + k*4 + d] = acc;
}

// ---------------- per-edge tensor product + norms + vec mixing --------------
__global__ __launch_bounds__(64) void edge_final_kernel(
    const float* __restrict__ eq_feat, const float* __restrict__ env2,
    const int* __restrict__ ctr,
    const float* __restrict__ eq_norm_w, const float* __restrict__ tp_norm_w,
    const float* __restrict__ lin_vec_w, float* __restrict__ out)
{
  __shared__ float eqs[32];
  __shared__ float eqv[32][3];
  __shared__ float envv[32][4];
  __shared__ float osA[32][2];
  __shared__ float ov[96][3];
  __shared__ float red5[5][64];
  const int e = blockIdx.x, l = threadIdx.x;
  float* wrow = out + (size_t)e*OUT_D;
  float p_s = 0.f, p_v = 0.f;
  if (l < 32) {
    int m = l;
    float4 x = *(const float4*)(eq_feat + ((size_t)e*32 + m)*4);
    float w0 = wrow[256 + 2*m], w1 = wrow[257 + 2*m];
    float sw = x.x*w0, v0 = x.y*w1, v1 = x.z*w1, v2 = x.w*w1;
    eqs[m]=sw; eqv[m][0]=v0; eqv[m][1]=v1; eqv[m][2]=v2;
    p_s = sw*sw; p_v = v0*v0 + v1*v1 + v2*v2;
  } else {
    int m = l - 32;
    float4 e4 = *(const float4*)(env2 + ((size_t)ctr[e]*32 + m)*4);
    envv[m][0]=e4.x; envv[m][1]=e4.y; envv[m][2]=e4.z; envv[m][3]=e4.w;
  }
  red5[0][l] = p_s; red5[1][l] = p_v;
  __syncthreads();
  for (int off=32; off>0; off>>=1) {
    if (l<off){ red5[0][l]+=red5[0][l+off]; red5[1][l]+=red5[1][l+off]; }
    __syncthreads();
  }
  float inv_s = rsqrtf(red5[0][0]*(1.f/32.f)+EPS6);
  float inv_v = rsqrtf(red5[1][0]*(1.f/96.f)+EPS6);
  __syncthreads();

  float ps[5] = {0,0,0,0,0};
  if (l < 32) {
    int m = l;
    float s  = eqs[m]*inv_s*eq_norm_w[2*m];
    float fv = inv_v*eq_norm_w[2*m+1];
    float v0 = eqv[m][0]*fv, v1 = eqv[m][1]*fv, v2 = eqv[m][2]*fv;
    float es = envv[m][0], e0 = envv[m][1], e1 = envv[m][2], e2 = envv[m][3];
    float os0 = s*es;
    float os1 = (v0*e0 + v1*e1 + v2*e2) * 0.5773502691896258f; // 1/sqrt3
    float a00=s*e0, a01=s*e1, a02=s*e2;
    float a10=v0*es, a11=v1*es, a12=v2*es;
    const float is2 = 0.7071067811865476f;                     // 1/sqrt2
    float a20=(v1*e2 - v2*e1)*is2;
    float a21=(v2*e0 - v0*e2)*is2;
    float a22=(v0*e1 - v1*e0)*is2;
    osA[m][0]=os0; osA[m][1]=os1;
    ov[m*3+0][0]=a00; ov[m*3+0][1]=a01; ov[m*3+0][2]=a02;
    ov[m*3+1][0]=a10; ov[m*3+1][1]=a11; ov[m*3+1][2]=a12;
    ov[m*3+2][0]=a20; ov[m*3+2][1]=a21; ov[m*3+2][2]=a22;
    ps[0]=os0*os0; ps[1]=os1*os1;
    ps[2]=a00*a00+a01*a01+a02*a02;
    ps[3]=a10*a10+a11*a11+a12*a12;
    ps[4]=a20*a20+a21*a21+a22*a22;
  }
  #pragma unroll
  for (int q=0;q<5;++q) red5[q][l] = ps[q];
  __syncthreads();
  for (int off=32; off>0; off>>=1) {
    if (l<off){
      #pragma unroll
      for (int q=0;q<5;++q) red5[q][l] += red5[q][l+off];
    }
    __syncthreads();
  }
  float t0 = rsqrtf(red5[0][0]*(1.f/32.f)+EPS6);
  float t1 = rsqrtf(red5[1][0]*(1.f/32.f)+EPS6);
  float r0 = rsqrtf(red5[2][0]*(1.f/96.f)+EPS6);
  float r1 = rsqrtf(red5[3][0]*(1.f/96.f)+EPS6);
  float r2 = rsqrtf(red5[4][0]*(1.f/96.f)+EPS6);

  if (l < 32) {
    int m = l;
    wrow[256 + 2*m]   = osA[m][0]*t0*tp_norm_w[m*5+0];
    wrow[257 + 2*m]   = osA[m][1]*t1*tp_norm_w[m*5+1];
    float f0 = r0*tp_norm_w[m*5+2];
    float f1 = r1*tp_norm_w[m*5+3];
    float f2 = r2*tp_norm_w[m*5+4];
    ov[m*3+0][0]*=f0; ov[m*3+0][1]*=f0; ov[m*3+0][2]*=f0;
    ov[m*3+1][0]*=f1; ov[m*3+1][1]*=f1; ov[m*3+1][2]*=f1;
    ov[m*3+2][0]*=f2; ov[m*3+2][1]*=f2; ov[m*3+2][2]*=f2;
  }
  __syncthreads();

  for (int idx = l; idx < 96; idx += 64) {
    int o = idx / 3, c = idx - o*3;
    float acc = 0.f;
    #pragma unroll 8
    for (int i=0;i<96;++i) acc += ov[i][c] * lin_vec_w[i*32 + o];
    wrow[320 + idx] = acc;   // vec layout: o*3 + c
  }
}

// =============================================================================
extern "C" void kernel_launch(void* const* d_in, const int* in_sizes, int n_in,
                              void* d_out, int out_size, void* d_ws, size_t ws_size,
                              hipStream_t stream)
{
  (void)in_sizes; (void)n_in; (void)out_size; (void)ws_size;
  const float* x      = (const float*)d_in[0];
  const float* cut    = (const float*)d_in[1];
  const float* eqf    = (const float*)d_in[2];
  const float* eattr  = (const float*)d_in[3];
  const float* ninv   = (const float*)d_in[4];
  const float* einv   = (const float*)d_in[5];
  const float* W1     = (const float*)d_in[6];
  const float* b1     = (const float*)d_in[7];
  const float* W2     = (const float*)d_in[8];
  const float* b2     = (const float*)d_in[9];
  const float* ln_g   = (const float*)d_in[10];
  const float* ln_b   = (const float*)d_in[11];
  const float* We1    = (const float*)d_in[12];
  const float* be1    = (const float*)d_in[13];
  const float* We2    = (const float*)d_in[14];
  const float* be2    = (const float*)d_in[15];
  const float* Wq     = (const float*)d_in[16];
  const float* Wk     = (const float*)d_in[17];
  const float* eq_nw  = (const float*)d_in[18];
  const float* env_nw = (const float*)d_in[19];
  const float* env_lw = (const float*)d_in[20];
  const float* tp_nw  = (const float*)d_in[21];
  const float* lin_vw = (const float*)d_in[22];
  const int*   ctr    = (const int*)d_in[23];
  const int*   nbr    = (const int*)d_in[24];

  float* out = (float*)d_out;
  float* ws  = (float*)d_ws;
  float* H        = ws + WS_H;
  float* att      = ws + WS_ATT;
  unsigned* nmax  = (unsigned*)(ws + WS_NMAX);
  float* nsum     = ws + WS_NSUM;
  float* env      = ws + WS_ENV;
  float* env2     = ws + WS_ENV2;

  // zero node_max (encode(-inf) < 0 for all reals? keys of reals > 0, so 0 is identity),
  // node_sum, env
  hipMemsetAsync(ws + WS_NMAX, 0, (size_t)(262144ull*2 + 1048576ull)*4, stream);

  dim3 blk(256);
  // G1: silu(X @ W1 + b1) -> H
  gemm_kernel<1><<<dim3(4, E_EDGES/64), blk, 0, stream>>>(x, D_INF, W1, L_DIM, b1, H, L_DIM, L_DIM, D_INF);
  // G2: H @ W2 + b2 -> d_out cols 0..255
  gemm_kernel<0><<<dim3(4, E_EDGES/64), blk, 0, stream>>>(H, L_DIM, W2, L_DIM, b2, out, OUT_D, L_DIM, L_DIM);
  // LayerNorm + cutoff (in place, d_out cols 0..255 -> latents)
  ln_cutoff_kernel<<<E_EDGES, 256, 0, stream>>>(out, ln_g, ln_b, cut);
  // G3: silu(latents @ We1 + be1) -> H
  gemm_kernel<1><<<dim3(4, E_EDGES/64), blk, 0, stream>>>(out, OUT_D, We1, L_DIM, be1, H, L_DIM, L_DIM, L_DIM);
  // G4: H @ We2 + be2 -> d_out cols 256..415 (weights)
  gemm_kernel<0><<<dim3(3, E_EDGES/64), blk, 0, stream>>>(H, L_DIM, We2, NW_DIM, be2, out + 256, OUT_D, NW_DIM, L_DIM);
  // QK logits, chunked through H
  for (int c = 0; c < 4; ++c) {
    int e0 = c * CHUNK;
    gemm_efa_kernel<<<dim3(8, CHUNK/64), blk, 0, stream>>>(ninv, einv, ctr, nbr, e0, Wq, H);
    gemm_kernel<0><<<dim3(8, CHUNK/64), blk, 0, stream>>>(out + (size_t)e0*OUT_D, OUT_D, Wk, QK_DIM,
                                                          nullptr, H + (size_t)CHUNK*QK_DIM, QK_DIM,
                                                          QK_DIM, L_DIM);
    qk_dot_kernel<<<(CHUNK*32)/256, 256, 0, stream>>>(H, H + (size_t)CHUNK*QK_DIM, att, e0);
  }
  // scatter softmax
  seg_max_kernel<<<(E_EDGES*32)/256, 256, 0, stream>>>(att, ctr, nmax);
  seg_expsum_kernel<<<(E_EDGES*32)/256, 256, 0, stream>>>(att, ctr, nmax, nsum);
  // env accumulation
  env_accum_kernel<<<(E_EDGES*32)/256, 256, 0, stream>>>(att, ctr, nsum, eattr, out, env);
  // env so3_norm + mixing
  env_post_kernel<<<N_NODES, 128, 0, stream>>>(env, env_nw, env_lw, env2);
  // final per-edge tensor product
  edge_final_kernel<<<E_EDGES, 64, 0, stream>>>(eqf, env2, ctr, eq_nw, tp_nw, lin_vw, out);
}

// Round 4
// 1493.286 us; speedup vs baseline: 1.6601x; 1.6601x over previous
//
#include <hip/hip_runtime.h>
#include <cstddef>
#include <cstdint>

// Problem constants (fixed by setup_inputs)
#define E_EDGES 131072
#define N_NODES 8192
#define D_INF   192
#define L_DIM   256
#define OUT_D   416
#define QK_CH   16384          // QK chunk (8 chunks)
#define EPS6    1e-6f
#define GAPAD   56

// ws layout (float offsets)
#define WS_H     0ull          // E*256 ushort (H_hi); later H2_hi
#define WS_QK    16777216ull   // E*256 ushort (H_lo / H2_lo); later Qb/Kb f32 scratch
#define WS_ATT   33554432ull   // E*32 f32
#define WS_NMAX  37748736ull   // N*32 u32
#define WS_NSUM  38010880ull   // N*32 f32
#define WS_ENV   38273024ull   // N*32*4 f32
#define WS_ENV2  39321600ull   // N*32*4 f32
#define WS_WB    40370176ull   // bf16 weight planes (917504 ushorts)

// WB ushort offsets (hi/lo pairs for all six weights)
#define WB_W1H   0
#define WB_W1L   49152
#define WB_W2H   98304
#define WB_W2L   163840
#define WB_WE1H  229376
#define WB_WE1L  294912
#define WB_WE2H  360448
#define WB_WE2L  409600
#define WB_WQH   458752
#define WB_WQL   557056
#define WB_WKH   655360
#define WB_WKL   786432

typedef __attribute__((ext_vector_type(8))) short bf16x8;
typedef __attribute__((ext_vector_type(4))) float f32x4;

__device__ __forceinline__ ushort f2bf(float f){
  unsigned u = __float_as_uint(f);
  unsigned r = u + 0x7fffu + ((u>>16)&1u);
  return (ushort)(r>>16);
}
__device__ __forceinline__ float bf2f(ushort h){
  return __uint_as_float(((unsigned)h)<<16);
}
__device__ __forceinline__ void split2(float v, ushort &h, ushort &l){
  h = f2bf(v);
  l = f2bf(v - bf2f(h));
}

// ---------------- weight transpose+convert: Wt[n][k] = bf16(W[k][n]) --------
__global__ __launch_bounds__(256) void wconv_kernel(
    const float* __restrict__ W, ushort* __restrict__ Whi,
    ushort* __restrict__ Wlo, int K, int N, int Npad)
{
  int idx = blockIdx.x*256 + threadIdx.x;
  if (idx >= Npad*K) return;
  int n = idx / K, k = idx - n*K;
  float v = (n < N) ? W[(size_t)k*N + n] : 0.f;
  ushort h = f2bf(v);
  Whi[idx] = h;
  Wlo[idx] = f2bf(v - bf2f(h));
}

// ---------------- bf16-split MFMA GEMM: C = act(A@W + bias) ------------------
// BM=128, BN=64, BK=32, 4 waves. B planes are (Npad,K) bf16 row-major.
// AMODE: 0 = A f32 row-major (split-staged), 2 = efa gather (f32, split),
//        3 = A bf16 hi/lo pair (Aptr=hi, Aptr2=lo)
// OMODE: 0 = f32 C, 2 = bf16 hi/lo pair C (Cptr, Cptr2)
// All GEMMs use hi/lo split: 3 MFMA per slot (near-f32 product).
template<int ACT, int AMODE, int OMODE>
__global__ __launch_bounds__(256) void mfma_gemm(
    const void* __restrict__ Aptr, const void* __restrict__ Aptr2, int lda,
    const ushort* __restrict__ Bhi, const ushort* __restrict__ Blo, int Kdim,
    const float* __restrict__ bias,
    void* __restrict__ Cptr, void* __restrict__ Cptr2, int ldc, int Ncols,
    const float* __restrict__ ninv, const float* __restrict__ einv,
    const int* __restrict__ ctr, const int* __restrict__ nbr, int e0)
{
  constexpr int ALO = 128*GAPAD;
  constexpr int BLO = 64*GAPAD;
  __shared__ ushort As[2*128*GAPAD];
  __shared__ ushort Bs[2*64*GAPAD];
  const int tid  = threadIdx.x;
  const int row0 = blockIdx.y * 128;
  const int n0   = blockIdx.x * 64;
  const int srow = tid >> 2;          // 0..63
  const int skc  = (tid & 3) * 8;     // 0,8,16,24
  const int w    = tid >> 6, lane = tid & 63;
  const int wm   = w >> 1,  wn   = w & 1;
  const int lr   = lane & 15, kg = lane >> 4;

  f32x4 acc[4][2];
  #pragma unroll
  for (int mi=0;mi<4;++mi)
    #pragma unroll
    for (int ni=0;ni<2;++ni) acc[mi][ni] = (f32x4){0.f,0.f,0.f,0.f};

  for (int k0 = 0; k0 < Kdim; k0 += 32) {
    // stage B tile (64 x 32 bf16), hi+lo
    *(bf16x8*)(Bs + srow*GAPAD + skc) =
        *(const bf16x8*)(Bhi + (size_t)(n0 + srow)*Kdim + k0 + skc);
    *(bf16x8*)(Bs + BLO + srow*GAPAD + skc) =
        *(const bf16x8*)(Blo + (size_t)(n0 + srow)*Kdim + k0 + skc);
    // stage A tile (128 x 32 bf16), hi+lo
    #pragma unroll
    for (int rep = 0; rep < 2; ++rep) {
      const int row = rep*64 + srow;
      ushort* dst = As + row*GAPAD + skc;
      if (AMODE == 3) {
        const size_t off = (size_t)(row0+row)*lda + k0 + skc;
        *(bf16x8*)dst = *(const bf16x8*)((const ushort*)Aptr + off);
        *(bf16x8*)(dst + ALO) = *(const bf16x8*)((const ushort*)Aptr2 + off);
      } else {
        const float* ap;
        if (AMODE == 0) {
          ap = (const float*)Aptr + (size_t)(row0+row)*lda + k0 + skc;
        } else {
          const int e = e0 + row0 + row;
          const int k = k0 + skc;
          if (k < 64)        ap = ninv + (size_t)ctr[e]*64 + k;
          else if (k < 128)  ap = ninv + (size_t)nbr[e]*64 + (k-64);
          else               ap = einv + (size_t)e*64 + (k-128);
        }
        float4 f0 = *(const float4*)ap;
        float4 f1 = *(const float4*)(ap+4);
        float vs[8] = {f0.x,f0.y,f0.z,f0.w,f1.x,f1.y,f1.z,f1.w};
        union { ushort u[8]; bf16x8 v; } th, tl;
        #pragma unroll
        for (int j=0;j<8;++j) split2(vs[j], th.u[j], tl.u[j]);
        *(bf16x8*)dst = th.v;
        *(bf16x8*)(dst + ALO) = tl.v;
      }
    }
    __syncthreads();
    bf16x8 ah[4], bh[2], al[4], bl[2];
    #pragma unroll
    for (int mi=0;mi<4;++mi) {
      ah[mi] = *(const bf16x8*)(As + (wm*64 + mi*16 + lr)*GAPAD + kg*8);
      al[mi] = *(const bf16x8*)(As + ALO + (wm*64 + mi*16 + lr)*GAPAD + kg*8);
    }
    #pragma unroll
    for (int ni=0;ni<2;++ni) {
      bh[ni] = *(const bf16x8*)(Bs + (wn*32 + ni*16 + lr)*GAPAD + kg*8);
      bl[ni] = *(const bf16x8*)(Bs + BLO + (wn*32 + ni*16 + lr)*GAPAD + kg*8);
    }
    #pragma unroll
    for (int mi=0;mi<4;++mi)
      #pragma unroll
      for (int ni=0;ni<2;++ni) {
        acc[mi][ni] = __builtin_amdgcn_mfma_f32_16x16x32_bf16(al[mi], bh[ni], acc[mi][ni], 0, 0, 0);
        acc[mi][ni] = __builtin_amdgcn_mfma_f32_16x16x32_bf16(ah[mi], bl[ni], acc[mi][ni], 0, 0, 0);
        acc[mi][ni] = __builtin_amdgcn_mfma_f32_16x16x32_bf16(ah[mi], bh[ni], acc[mi][ni], 0, 0, 0);
      }
    __syncthreads();
  }
  // epilogue: C/D layout col=lane&15, row=(lane>>4)*4+r  [m89-verified]
  #pragma unroll
  for (int ni=0;ni<2;++ni) {
    const int col = n0 + wn*32 + ni*16 + lr;
    if (col < Ncols) {
      const float bv = bias ? bias[col] : 0.f;
      #pragma unroll
      for (int mi=0;mi<4;++mi) {
        #pragma unroll
        for (int r=0;r<4;++r) {
          const int row = row0 + wm*64 + mi*16 + kg*4 + r;
          float v = acc[mi][ni][r] + bv;
          if (ACT == 1) v = v / (1.f + __expf(-v));
          const size_t oidx = (size_t)row*ldc + col;
          if (OMODE == 0) ((float*)Cptr)[oidx] = v;
          else {
            ushort h, l; split2(v, h, l);
            ((ushort*)Cptr)[oidx]  = h;
            ((ushort*)Cptr2)[oidx] = l;
          }
        }
      }
    }
  }
}

// ---------------- LayerNorm + cutoff (in place on d_out cols 0..255) --------
__global__ __launch_bounds__(256) void ln_cutoff_kernel(
    float* __restrict__ out, const float* __restrict__ g,
    const float* __restrict__ b, const float* __restrict__ cut)
{
  __shared__ float2 wp[4];
  const int e = blockIdx.x, t = threadIdx.x;
  const int w = t >> 6, lane = t & 63;
  float v = out[(size_t)e*OUT_D + t];
  float s = v, s2 = v*v;
  #pragma unroll
  for (int off=32; off; off>>=1) {
    s  += __shfl_xor(s,  off, 64);
    s2 += __shfl_xor(s2, off, 64);
  }
  if (lane == 0) wp[w] = make_float2(s, s2);
  __syncthreads();
  float ts  = wp[0].x + wp[1].x + wp[2].x + wp[3].x;
  float ts2 = wp[0].y + wp[1].y + wp[2].y + wp[3].y;
  float mean = ts * (1.f/256.f);
  float var  = ts2 * (1.f/256.f) - mean*mean;
  float nv = (v - mean) * rsqrtf(var + 1e-5f) * g[t] + b[t];
  if (t < 128) nv *= cut[e];
  out[(size_t)e*OUT_D + t] = nv;
}

// ---------------- QK dot: logits[e,m] = 4 * sum_d Q*K -----------------------
__global__ __launch_bounds__(256) void qk_dot_kernel(
    const float* __restrict__ Q, const float* __restrict__ K,
    float* __restrict__ att, int e0)
{
  const int tid = blockIdx.x * 256 + threadIdx.x;
  const int le = tid >> 5, m = tid & 31;
  const float* q = Q + (size_t)le*512 + m*16;
  const float* k = K + (size_t)le*512 + m*16;
  float s = 0.f;
  #pragma unroll
  for (int d=0; d<16; d+=4) {
    float4 qv = *(const float4*)(q+d);
    float4 kv = *(const float4*)(k+d);
    s += qv.x*kv.x + qv.y*kv.y + qv.z*kv.z + qv.w*kv.w;
  }
  att[(size_t)(e0+le)*32 + m] = 4.0f * s;
}

// ---------------- scatter softmax helpers -----------------------------------
__device__ __forceinline__ unsigned fenc(float x){
  unsigned u = __float_as_uint(x);
  return (u & 0x80000000u) ? ~u : (u | 0x80000000u);
}
__device__ __forceinline__ float fdec(unsigned k){
  return (k & 0x80000000u) ? __uint_as_float(k & 0x7fffffffu) : __uint_as_float(~k);
}

__global__ __launch_bounds__(256) void seg_max_kernel(
    const float* __restrict__ att, const int* __restrict__ ctr,
    unsigned* __restrict__ nmax)
{
  const int tid = blockIdx.x*256 + threadIdx.x;
  const int e = tid >> 5, m = tid & 31;
  atomicMax(&nmax[(size_t)ctr[e]*32 + m], fenc(att[tid]));
}

__global__ __launch_bounds__(256) void seg_expsum_kernel(
    float* __restrict__ att, const int* __restrict__ ctr,
    const unsigned* __restrict__ nmax, float* __restrict__ nsum)
{
  const int tid = blockIdx.x*256 + threadIdx.x;
  const int e = tid >> 5, m = tid & 31;
  const size_t ci = (size_t)ctr[e]*32 + m;
  float ex = __expf(att[tid] - fdec(nmax[ci]));
  att[tid] = ex;
  atomicAdd(&nsum[ci], ex);
}

// ---------------- env accumulation (emb * att scattered to nodes) -----------
__global__ __launch_bounds__(256) void env_accum_kernel(
    const float* __restrict__ att, const int* __restrict__ ctr,
    const float* __restrict__ nsum, const float* __restrict__ edge_attr,
    const float* __restrict__ outbuf, float* __restrict__ env)
{
  const int tid = blockIdx.x*256 + threadIdx.x;
  const int e = tid >> 5, m = tid & 31;
  const size_t ci = (size_t)ctr[e]*32 + m;
  float a = att[tid] / (nsum[ci] + 1e-16f);
  const float* wr = outbuf + (size_t)e*OUT_D + 256;
  float w0 = wr[64 + 2*m], w1 = wr[65 + 2*m], sc = wr[128 + m];
  float4 ea = *(const float4*)(edge_attr + ((size_t)e*32 + m)*4);
  float cs = sc * a;
  float* dst = env + ci*4;
  atomicAdd(dst+0, ea.x*w0*cs);
  atomicAdd(dst+1, ea.y*w1*cs);
  atomicAdd(dst+2, ea.z*w1*cs);
  atomicAdd(dst+3, ea.w*w1*cs);
}

// ---------------- env so3_norm + channel mixing ------------------------------
__global__ __launch_bounds__(128) void env_post_kernel(
    const float* __restrict__ env, const float* __restrict__ env_norm_w,
    const float* __restrict__ env_lin_w, float* __restrict__ env2)
{
  __shared__ float ev[128];
  __shared__ float2 red[128];
  const int n = blockIdx.x, t = threadIdx.x;
  const int d = t & 3, k = t >> 2;
  float val = env[(size_t)n*128 + t];
  red[t] = make_float2(d==0 ? val*val : 0.f, d!=0 ? val*val : 0.f);
  __syncthreads();
  for (int off=64; off>0; off>>=1) {
    if (t<off){ red[t].x += red[t+off].x; red[t].y += red[t+off].y; }
    __syncthreads();
  }
  float inv_s = rsqrtf(red[0].x*(1.f/32.f)+EPS6);
  float inv_v = rsqrtf(red[0].y*(1.f/96.f)+EPS6);
  float nv = (d==0) ? val*inv_s*env_norm_w[2*k] : val*inv_v*env_norm_w[2*k+1];
  ev[t] = nv;
  __syncthreads();
  const float* WL = env_lin_w + (d==0 ? 0 : 1024);
  float acc = 0.f;
  #pragma unroll 8
  for (int m=0;m<32;++m) acc += ev[m*4+d]*WL[m*32+k];
  env2[(size_t)n*128 + k*4 + d] = acc;
}

// ---------------- per-edge tensor product: 32 lanes/edge, 8 edges/block -----
__global__ __launch_bounds__(256) void edge_final_kernel(
    const float* __restrict__ eq_feat, const float* __restrict__ env2,
    const int* __restrict__ ctr,
    const float* __restrict__ eq_norm_w, const float* __restrict__ tp_norm_w,
    const float* __restrict__ lin_vec_w, float* __restrict__ out)
{
  __shared__ float Wv[96*32];
  __shared__ float ov[8][96][3];
  const int tid = threadIdx.x;
  for (int i = tid; i < 96*32; i += 256) Wv[i] = lin_vec_w[i];
  __syncthreads();
  const int grp = tid >> 5;
  const int m   = tid & 31;
  const int e   = blockIdx.x*8 + grp;
  float* wrow = out + (size_t)e*OUT_D;

  float4 x   = *(const float4*)(eq_feat + ((size_t)e*32 + m)*4);
  float2 w01 = *(const float2*)(wrow + 256 + 2*m);
  float sw = x.x*w01.x, v0 = x.y*w01.y, v1 = x.z*w01.y, v2 = x.w*w01.y;
  const int nidx = ctr[e];
  float4 evv = *(const float4*)(env2 + (size_t)nidx*128 + m*4);

  float ps_ = sw*sw, pv_ = v0*v0 + v1*v1 + v2*v2;
  #pragma unroll
  for (int off=16; off; off>>=1) {
    ps_ += __shfl_xor(ps_, off, 32);
    pv_ += __shfl_xor(pv_, off, 32);
  }
  float inv_s = rsqrtf(ps_*(1.f/32.f)+EPS6);
  float inv_v = rsqrtf(pv_*(1.f/96.f)+EPS6);
  float s  = sw*inv_s*eq_norm_w[2*m];
  float fv = inv_v*eq_norm_w[2*m+1];
  v0 *= fv; v1 *= fv; v2 *= fv;
  float es = evv.x, e0 = evv.y, e1 = evv.z, e2 = evv.w;
  float os0 = s*es;
  float os1 = (v0*e0 + v1*e1 + v2*e2) * 0.5773502691896258f;
  float a00=s*e0, a01=s*e1, a02=s*e2;
  float a10=v0*es, a11=v1*es, a12=v2*es;
  const float is2 = 0.7071067811865476f;
  float a20=(v1*e2 - v2*e1)*is2;
  float a21=(v2*e0 - v0*e2)*is2;
  float a22=(v0*e1 - v1*e0)*is2;
  float q0 = os0*os0, q1 = os1*os1;
  float q2 = a00*a00+a01*a01+a02*a02;
  float q3 = a10*a10+a11*a11+a12*a12;
  float q4 = a20*a20+a21*a21+a22*a22;
  #pragma unroll
  for (int off=16; off; off>>=1) {
    q0 += __shfl_xor(q0, off, 32); q1 += __shfl_xor(q1, off, 32);
    q2 += __shfl_xor(q2, off, 32); q3 += __shfl_xor(q3, off, 32);
    q4 += __shfl_xor(q4, off, 32);
  }
  float t0 = rsqrtf(q0*(1.f/32.f)+EPS6)*tp_norm_w[m*5+0];
  float t1 = rsqrtf(q1*(1.f/32.f)+EPS6)*tp_norm_w[m*5+1];
  float f0 = rsqrtf(q2*(1.f/96.f)+EPS6)*tp_norm_w[m*5+2];
  float f1 = rsqrtf(q3*(1.f/96.f)+EPS6)*tp_norm_w[m*5+3];
  float f2 = rsqrtf(q4*(1.f/96.f)+EPS6)*tp_norm_w[m*5+4];

  *(float2*)(wrow + 256 + 2*m) = make_float2(os0*t0, os1*t1);
  ov[grp][3*m+0][0]=a00*f0; ov[grp][3*m+0][1]=a01*f0; ov[grp][3*m+0][2]=a02*f0;
  ov[grp][3*m+1][0]=a10*f1; ov[grp][3*m+1][1]=a11*f1; ov[grp][3*m+1][2]=a12*f1;
  ov[grp][3*m+2][0]=a20*f2; ov[grp][3*m+2][1]=a21*f2; ov[grp][3*m+2][2]=a22*f2;
  float acc0=0.f, acc1=0.f, acc2=0.f;
  #pragma unroll 4
  for (int i=0;i<96;++i) {
    float wv = Wv[i*32 + m];
    acc0 += ov[grp][i][0]*wv;
    acc1 += ov[grp][i][1]*wv;
    acc2 += ov[grp][i][2]*wv;
  }
  wrow[320 + 3*m + 0] = acc0;
  wrow[320 + 3*m + 1] = acc1;
  wrow[320 + 3*m + 2] = acc2;
}

// =============================================================================
extern "C" void kernel_launch(void* const* d_in, const int* in_sizes, int n_in,
                              void* d_out, int out_size, void* d_ws, size_t ws_size,
                              hipStream_t stream)
{
  (void)in_sizes; (void)n_in; (void)out_size; (void)ws_size;
  const float* x      = (const float*)d_in[0];
  const float* cut    = (const float*)d_in[1];
  const float* eqf    = (const float*)d_in[2];
  const float* eattr  = (const float*)d_in[3];
  const float* ninv   = (const float*)d_in[4];
  const float* einv   = (const float*)d_in[5];
  const float* W1     = (const float*)d_in[6];
  const float* b1     = (const float*)d_in[7];
  const float* W2     = (const float*)d_in[8];
  const float* b2     = (const float*)d_in[9];
  const float* ln_g   = (const float*)d_in[10];
  const float* ln_b   = (const float*)d_in[11];
  const float* We1    = (const float*)d_in[12];
  const float* be1    = (const float*)d_in[13];
  const float* We2    = (const float*)d_in[14];
  const float* be2    = (const float*)d_in[15];
  const float* Wq     = (const float*)d_in[16];
  const float* Wk     = (const float*)d_in[17];
  const float* eq_nw  = (const float*)d_in[18];
  const float* env_nw = (const float*)d_in[19];
  const float* env_lw = (const float*)d_in[20];
  const float* tp_nw  = (const float*)d_in[21];
  const float* lin_vw = (const float*)d_in[22];
  const int*   ctr    = (const int*)d_in[23];
  const int*   nbr    = (const int*)d_in[24];

  float* out = (float*)d_out;
  float* ws  = (float*)d_ws;
  ushort* Hhi   = (ushort*)(ws + WS_H);     // E x 256 bf16 hi (G1 out, then G3 out hi)
  ushort* Hlo   = (ushort*)(ws + WS_QK);    // E x 256 bf16 lo (G1 out, then G3 out lo)
  float* Qb     = ws + WS_QK;               // reuses lo region after G4
  float* Kb     = Qb + (size_t)QK_CH*512;
  float* att    = ws + WS_ATT;
  unsigned* nmax= (unsigned*)(ws + WS_NMAX);
  float* nsum   = ws + WS_NSUM;
  float* env    = ws + WS_ENV;
  float* env2   = ws + WS_ENV2;
  ushort* WB    = (ushort*)(ws + WS_WB);

  hipMemsetAsync(ws + WS_NMAX, 0, (size_t)(262144ull*2 + 1048576ull)*4, stream);

  // weight conversion (transposed, zero-padded rows, hi/lo planes)
  wconv_kernel<<<192, 256, 0, stream>>>(W1,  WB+WB_W1H,  WB+WB_W1L,  192, 256, 256);
  wconv_kernel<<<256, 256, 0, stream>>>(W2,  WB+WB_W2H,  WB+WB_W2L,  256, 256, 256);
  wconv_kernel<<<256, 256, 0, stream>>>(We1, WB+WB_WE1H, WB+WB_WE1L, 256, 256, 256);
  wconv_kernel<<<192, 256, 0, stream>>>(We2, WB+WB_WE2H, WB+WB_WE2L, 256, 160, 192);
  wconv_kernel<<<384, 256, 0, stream>>>(Wq,  WB+WB_WQH,  WB+WB_WQL,  192, 512, 512);
  wconv_kernel<<<512, 256, 0, stream>>>(Wk,  WB+WB_WKH,  WB+WB_WKL,  256, 512, 512);

  dim3 blk(256);
  // G1 (split): silu(x @ W1 + b1) -> H hi/lo
  mfma_gemm<1,0,2><<<dim3(4, E_EDGES/128), blk, 0, stream>>>(
      x, nullptr, D_INF, WB+WB_W1H, WB+WB_W1L, 192, b1,
      Hhi, Hlo, 256, 256, nullptr,nullptr,nullptr,nullptr,0);
  // G2 (split): H @ W2 + b2 -> d_out cols 0..255 (f32)
  mfma_gemm<0,3,0><<<dim3(4, E_EDGES/128), blk, 0, stream>>>(
      Hhi, Hlo, 256, WB+WB_W2H, WB+WB_W2L, 256, b2,
      out, nullptr, OUT_D, 256, nullptr,nullptr,nullptr,nullptr,0);
  // LayerNorm + cutoff (f32, in place)
  ln_cutoff_kernel<<<E_EDGES, 256, 0, stream>>>(out, ln_g, ln_b, cut);
  // G3 (split): silu(lat @ We1 + be1) -> H2 hi/lo (reuses H regions)
  mfma_gemm<1,0,2><<<dim3(4, E_EDGES/128), blk, 0, stream>>>(
      out, nullptr, OUT_D, WB+WB_WE1H, WB+WB_WE1L, 256, be1,
      Hhi, Hlo, 256, 256, nullptr,nullptr,nullptr,nullptr,0);
  // G4 (split): H2 @ We2 + be2 -> d_out cols 256..415 (f32)
  mfma_gemm<0,3,0><<<dim3(3, E_EDGES/128), blk, 0, stream>>>(
      Hhi, Hlo, 256, WB+WB_WE2H, WB+WB_WE2L, 256, be2,
      out + 256, nullptr, OUT_D, 160, nullptr,nullptr,nullptr,nullptr,0);
  // QK phase (split), chunked through retired Hlo region
  for (int c = 0; c < E_EDGES/QK_CH; ++c) {
    const int e0 = c * QK_CH;
    mfma_gemm<0,2,0><<<dim3(8, QK_CH/128), blk, 0, stream>>>(
        nullptr, nullptr, 0, WB+WB_WQH, WB+WB_WQL, 192, nullptr,
        Qb, nullptr, 512, 512, ninv, einv, ctr, nbr, e0);
    mfma_gemm<0,0,0><<<dim3(8, QK_CH/128), blk, 0, stream>>>(
        out + (size_t)e0*OUT_D, nullptr, OUT_D, WB+WB_WKH, WB+WB_WKL, 256, nullptr,
        Kb, nullptr, 512, 512, nullptr,nullptr,nullptr,nullptr,0);
    qk_dot_kernel<<<(QK_CH*32)/256, 256, 0, stream>>>(Qb, Kb, att, e0);
  }
  // scatter softmax
  seg_max_kernel<<<(E_EDGES*32)/256, 256, 0, stream>>>(att, ctr, nmax);
  seg_expsum_kernel<<<(E_EDGES*32)/256, 256, 0, stream>>>(att, ctr, nmax, nsum);
  // env accumulation
  env_accum_kernel<<<(E_EDGES*32)/256, 256, 0, stream>>>(att, ctr, nsum, eattr, out, env);
  // env so3_norm + mixing
  env_post_kernel<<<N_NODES, 128, 0, stream>>>(env, env_nw, env_lw, env2);
  // final per-edge tensor product
  edge_final_kernel<<<E_EDGES/8, 256, 0, stream>>>(eqf, env2, ctr, eq_nw, tp_nw, lin_vw, out);
}

// Round 5
// 1304.014 us; speedup vs baseline: 1.9011x; 1.1451x over previous
//
#include <hip/hip_runtime.h>
#include <cstddef>
#include <cstdint>

// Problem constants (fixed by setup_inputs)
#define E_EDGES 131072
#define N_NODES 8192
#define D_INF   192
#define L_DIM   256
#define OUT_D   416
#define QK_CH   16384          // QK chunk (8 chunks)
#define EPS6    1e-6f
#define GAPAD   56

// ws layout (float offsets)
#define WS_H     0ull          // E*256 bf16 hi plane (G1/G3 out)
#define WS_QK    16777216ull   // E*256 bf16 lo plane; later Qb/Kb f32 scratch
#define WS_ATT   33554432ull   // E*32 f32 logits
#define WS_ENV2  37748736ull   // N*128 f32
#define WS_CNT   38797312ull   // N int
#define WS_ROWPTR 38805504ull  // N+1 int (padded)
#define WS_CURSOR 38813760ull  // N int
#define WS_EIDX  38821952ull   // E int
#define WS_WB    38953024ull   // bf16 weight planes (917504 ushorts)

// WB ushort offsets (hi/lo pairs for all six weights)
#define WB_W1H   0
#define WB_W1L   49152
#define WB_W2H   98304
#define WB_W2L   163840
#define WB_WE1H  229376
#define WB_WE1L  294912
#define WB_WE2H  360448
#define WB_WE2L  409600
#define WB_WQH   458752
#define WB_WQL   557056
#define WB_WKH   655360
#define WB_WKL   786432

typedef __attribute__((ext_vector_type(8))) short bf16x8;
typedef __attribute__((ext_vector_type(4))) float f32x4;

__device__ __forceinline__ ushort f2bf(float f){
  unsigned u = __float_as_uint(f);
  unsigned r = u + 0x7fffu + ((u>>16)&1u);
  return (ushort)(r>>16);
}
__device__ __forceinline__ float bf2f(ushort h){
  return __uint_as_float(((unsigned)h)<<16);
}
__device__ __forceinline__ void split2(float v, ushort &h, ushort &l){
  h = f2bf(v);
  l = f2bf(v - bf2f(h));
}

// ---------------- weight transpose+convert: Wt[n][k] = bf16(W[k][n]) --------
__global__ __launch_bounds__(256) void wconv_kernel(
    const float* __restrict__ W, ushort* __restrict__ Whi,
    ushort* __restrict__ Wlo, int K, int N, int Npad)
{
  int idx = blockIdx.x*256 + threadIdx.x;
  if (idx >= Npad*K) return;
  int n = idx / K, k = idx - n*K;
  float v = (n < N) ? W[(size_t)k*N + n] : 0.f;
  ushort h = f2bf(v);
  Whi[idx] = h;
  Wlo[idx] = f2bf(v - bf2f(h));
}

// ---------------- bf16-split MFMA GEMM: C = act(A@W + bias) ------------------
// BM=128, BN=64, BK=32, 4 waves. B planes are (Npad,K) bf16 row-major.
// AMODE: 0 = A f32 row-major (split-staged), 2 = efa gather (f32, split),
//        3 = A bf16 hi/lo pair (Aptr=hi, Aptr2=lo)
// OMODE: 0 = f32 C, 2 = bf16 hi/lo pair C (Cptr, Cptr2)
template<int ACT, int AMODE, int OMODE>
__global__ __launch_bounds__(256) void mfma_gemm(
    const void* __restrict__ Aptr, const void* __restrict__ Aptr2, int lda,
    const ushort* __restrict__ Bhi, const ushort* __restrict__ Blo, int Kdim,
    const float* __restrict__ bias,
    void* __restrict__ Cptr, void* __restrict__ Cptr2, int ldc, int Ncols,
    const float* __restrict__ ninv, const float* __restrict__ einv,
    const int* __restrict__ ctr, const int* __restrict__ nbr, int e0)
{
  constexpr int ALO = 128*GAPAD;
  constexpr int BLO = 64*GAPAD;
  __shared__ ushort As[2*128*GAPAD];
  __shared__ ushort Bs[2*64*GAPAD];
  const int tid  = threadIdx.x;
  const int row0 = blockIdx.y * 128;
  const int n0   = blockIdx.x * 64;
  const int srow = tid >> 2;          // 0..63
  const int skc  = (tid & 3) * 8;     // 0,8,16,24
  const int w    = tid >> 6, lane = tid & 63;
  const int wm   = w >> 1,  wn   = w & 1;
  const int lr   = lane & 15, kg = lane >> 4;

  f32x4 acc[4][2];
  #pragma unroll
  for (int mi=0;mi<4;++mi)
    #pragma unroll
    for (int ni=0;ni<2;++ni) acc[mi][ni] = (f32x4){0.f,0.f,0.f,0.f};

  for (int k0 = 0; k0 < Kdim; k0 += 32) {
    *(bf16x8*)(Bs + srow*GAPAD + skc) =
        *(const bf16x8*)(Bhi + (size_t)(n0 + srow)*Kdim + k0 + skc);
    *(bf16x8*)(Bs + BLO + srow*GAPAD + skc) =
        *(const bf16x8*)(Blo + (size_t)(n0 + srow)*Kdim + k0 + skc);
    #pragma unroll
    for (int rep = 0; rep < 2; ++rep) {
      const int row = rep*64 + srow;
      ushort* dst = As + row*GAPAD + skc;
      if (AMODE == 3) {
        const size_t off = (size_t)(row0+row)*lda + k0 + skc;
        *(bf16x8*)dst = *(const bf16x8*)((const ushort*)Aptr + off);
        *(bf16x8*)(dst + ALO) = *(const bf16x8*)((const ushort*)Aptr2 + off);
      } else {
        const float* ap;
        if (AMODE == 0) {
          ap = (const float*)Aptr + (size_t)(row0+row)*lda + k0 + skc;
        } else {
          const int e = e0 + row0 + row;
          const int k = k0 + skc;
          if (k < 64)        ap = ninv + (size_t)ctr[e]*64 + k;
          else if (k < 128)  ap = ninv + (size_t)nbr[e]*64 + (k-64);
          else               ap = einv + (size_t)e*64 + (k-128);
        }
        float4 f0 = *(const float4*)ap;
        float4 f1 = *(const float4*)(ap+4);
        float vs[8] = {f0.x,f0.y,f0.z,f0.w,f1.x,f1.y,f1.z,f1.w};
        union { ushort u[8]; bf16x8 v; } th, tl;
        #pragma unroll
        for (int j=0;j<8;++j) split2(vs[j], th.u[j], tl.u[j]);
        *(bf16x8*)dst = th.v;
        *(bf16x8*)(dst + ALO) = tl.v;
      }
    }
    __syncthreads();
    bf16x8 ah[4], bh[2], al[4], bl[2];
    #pragma unroll
    for (int mi=0;mi<4;++mi) {
      ah[mi] = *(const bf16x8*)(As + (wm*64 + mi*16 + lr)*GAPAD + kg*8);
      al[mi] = *(const bf16x8*)(As + ALO + (wm*64 + mi*16 + lr)*GAPAD + kg*8);
    }
    #pragma unroll
    for (int ni=0;ni<2;++ni) {
      bh[ni] = *(const bf16x8*)(Bs + (wn*32 + ni*16 + lr)*GAPAD + kg*8);
      bl[ni] = *(const bf16x8*)(Bs + BLO + (wn*32 + ni*16 + lr)*GAPAD + kg*8);
    }
    #pragma unroll
    for (int mi=0;mi<4;++mi)
      #pragma unroll
      for (int ni=0;ni<2;++ni) {
        acc[mi][ni] = __builtin_amdgcn_mfma_f32_16x16x32_bf16(al[mi], bh[ni], acc[mi][ni], 0, 0, 0);
        acc[mi][ni] = __builtin_amdgcn_mfma_f32_16x16x32_bf16(ah[mi], bl[ni], acc[mi][ni], 0, 0, 0);
        acc[mi][ni] = __builtin_amdgcn_mfma_f32_16x16x32_bf16(ah[mi], bh[ni], acc[mi][ni], 0, 0, 0);
      }
    __syncthreads();
  }
  #pragma unroll
  for (int ni=0;ni<2;++ni) {
    const int col = n0 + wn*32 + ni*16 + lr;
    if (col < Ncols) {
      const float bv = bias ? bias[col] : 0.f;
      #pragma unroll
      for (int mi=0;mi<4;++mi) {
        #pragma unroll
        for (int r=0;r<4;++r) {
          const int row = row0 + wm*64 + mi*16 + kg*4 + r;
          float v = acc[mi][ni][r] + bv;
          if (ACT == 1) v = v / (1.f + __expf(-v));
          const size_t oidx = (size_t)row*ldc + col;
          if (OMODE == 0) ((float*)Cptr)[oidx] = v;
          else {
            ushort h, l; split2(v, h, l);
            ((ushort*)Cptr)[oidx]  = h;
            ((ushort*)Cptr2)[oidx] = l;
          }
        }
      }
    }
  }
}

// ---------------- LayerNorm + cutoff (in place on d_out cols 0..255) --------
__global__ __launch_bounds__(256) void ln_cutoff_kernel(
    float* __restrict__ out, const float* __restrict__ g,
    const float* __restrict__ b, const float* __restrict__ cut)
{
  __shared__ float2 wp[4];
  const int e = blockIdx.x, t = threadIdx.x;
  const int w = t >> 6, lane = t & 63;
  float v = out[(size_t)e*OUT_D + t];
  float s = v, s2 = v*v;
  #pragma unroll
  for (int off=32; off; off>>=1) {
    s  += __shfl_xor(s,  off, 64);
    s2 += __shfl_xor(s2, off, 64);
  }
  if (lane == 0) wp[w] = make_float2(s, s2);
  __syncthreads();
  float ts  = wp[0].x + wp[1].x + wp[2].x + wp[3].x;
  float ts2 = wp[0].y + wp[1].y + wp[2].y + wp[3].y;
  float mean = ts * (1.f/256.f);
  float var  = ts2 * (1.f/256.f) - mean*mean;
  float nv = (v - mean) * rsqrtf(var + 1e-5f) * g[t] + b[t];
  if (t < 128) nv *= cut[e];
  out[(size_t)e*OUT_D + t] = nv;
}

// ---------------- QK dot: logits[e,m] = 4 * sum_d Q*K -----------------------
__global__ __launch_bounds__(256) void qk_dot_kernel(
    const float* __restrict__ Q, const float* __restrict__ K,
    float* __restrict__ att, int e0)
{
  const int tid = blockIdx.x * 256 + threadIdx.x;
  const int le = tid >> 5, m = tid & 31;
  const float* q = Q + (size_t)le*512 + m*16;
  const float* k = K + (size_t)le*512 + m*16;
  float s = 0.f;
  #pragma unroll
  for (int d=0; d<16; d+=4) {
    float4 qv = *(const float4*)(q+d);
    float4 kv = *(const float4*)(k+d);
    s += qv.x*kv.x + qv.y*kv.y + qv.z*kv.z + qv.w*kv.w;
  }
  att[(size_t)(e0+le)*32 + m] = 4.0f * s;
}

// ---------------- CSR build: histogram / scan / scatter ---------------------
__global__ __launch_bounds__(256) void hist_kernel(
    const int* __restrict__ ctr, int* __restrict__ cnt)
{
  int e = blockIdx.x*256 + threadIdx.x;
  if (e < E_EDGES) atomicAdd(&cnt[ctr[e]], 1);
}

__global__ __launch_bounds__(256) void scan_kernel(
    const int* __restrict__ cnt, int* __restrict__ rowptr,
    int* __restrict__ cursor)
{
  __shared__ int part[256];
  const int t = threadIdx.x;
  const int base = t*32;
  int local[32];
  int s = 0;
  #pragma unroll
  for (int k=0;k<32;++k){ local[k]=cnt[base+k]; s+=local[k]; }
  part[t]=s; __syncthreads();
  for (int off=1; off<256; off<<=1){
    int v = (t>=off)? part[t-off] : 0;
    __syncthreads();
    part[t]+=v;
    __syncthreads();
  }
  int run = (t==0)?0:part[t-1];
  #pragma unroll
  for (int k=0;k<32;++k){ rowptr[base+k]=run; cursor[base+k]=run; run+=local[k]; }
  if (t==255) rowptr[N_NODES]=run;
}

__global__ __launch_bounds__(256) void scatter_kernel(
    const int* __restrict__ ctr, int* __restrict__ cursor,
    int* __restrict__ eidx)
{
  int e = blockIdx.x*256 + threadIdx.x;
  if (e < E_EDGES){ int p = atomicAdd(&cursor[ctr[e]],1); eidx[p]=e; }
}

// ---------------- fused per-node: softmax + env accum + so3_norm + mixing ---
__global__ __launch_bounds__(128) void node_env_kernel(
    const float* __restrict__ att, const int* __restrict__ eidx,
    const int* __restrict__ rowptr, const float* __restrict__ eattr,
    const float* __restrict__ outbuf,
    const float* __restrict__ env_nw, const float* __restrict__ env_lw,
    float* __restrict__ env2)
{
  __shared__ float mx_s[32], rs_s[32];
  __shared__ float jm[4][32], js[4][32];
  __shared__ float ev[128];
  __shared__ float2 red[128];
  const int n = blockIdx.x, t = threadIdx.x;
  const int start = rowptr[n], deg = rowptr[n+1] - start;
  // phase 1: online softmax stats per (n,m), 4-way edge-strided
  {
    const int m = t & 31, j = t >> 5;
    float lm = -3.4e38f, ls = 0.f;
    for (int i = j; i < deg; i += 4) {
      float l = att[(size_t)eidx[start+i]*32 + m];
      if (l > lm) { ls = ls * __expf(lm - l) + 1.f; lm = l; }
      else ls += __expf(l - lm);
    }
    jm[j][m] = lm; js[j][m] = ls;
  }
  __syncthreads();
  if (t < 32) {
    const int m = t;
    float M = jm[0][m];
    #pragma unroll
    for (int q=1;q<4;++q) M = fmaxf(M, jm[q][m]);
    float S = 0.f;
    #pragma unroll
    for (int q=0;q<4;++q) S += js[q][m] * __expf(jm[q][m] - M);
    mx_s[m] = M;
    rs_s[m] = 1.f / (S + 1e-16f);
  }
  __syncthreads();
  // phase 2: env[m][d] accumulation over edge list
  const int m2 = t >> 2, d = t & 3;
  const float M2 = mx_s[m2], R2 = rs_s[m2];
  float acc = 0.f;
  for (int i = 0; i < deg; ++i) {
    const int e = eidx[start+i];
    float a = __expf(att[(size_t)e*32 + m2] - M2) * R2;
    const float* wr = outbuf + (size_t)e*OUT_D + 256;
    float w = (d==0) ? wr[64 + 2*m2] : wr[65 + 2*m2];
    float sc = wr[128 + m2];
    float ea = eattr[(size_t)e*128 + m2*4 + d];
    acc += ea * w * sc * a;
  }
  // phase 3: so3_norm + channel mixing -> env2
  float val = acc;
  red[t] = make_float2(d==0 ? val*val : 0.f, d!=0 ? val*val : 0.f);
  __syncthreads();
  for (int off=64; off>0; off>>=1) {
    if (t<off){ red[t].x += red[t+off].x; red[t].y += red[t+off].y; }
    __syncthreads();
  }
  float inv_s = rsqrtf(red[0].x*(1.f/32.f)+EPS6);
  float inv_v = rsqrtf(red[0].y*(1.f/96.f)+EPS6);
  float nv = (d==0) ? val*inv_s*env_nw[2*m2] : val*inv_v*env_nw[2*m2+1];
  ev[t] = nv;
  __syncthreads();
  const float* WL = env_lw + (d==0 ? 0 : 1024);
  float a2 = 0.f;
  #pragma unroll 8
  for (int q=0;q<32;++q) a2 += ev[q*4+d]*WL[q*32+m2];
  env2[(size_t)n*128 + m2*4 + d] = a2;
}

// ---------------- per-edge tensor product: 32 lanes/edge, 8 edges/block -----
__global__ __launch_bounds__(256) void edge_final_kernel(
    const float* __restrict__ eq_feat, const float* __restrict__ env2,
    const int* __restrict__ ctr,
    const float* __restrict__ eq_norm_w, const float* __restrict__ tp_norm_w,
    const float* __restrict__ lin_vec_w, float* __restrict__ out)
{
  __shared__ float Wv[96*32];
  __shared__ float ov[8][96][3];
  const int tid = threadIdx.x;
  for (int i = tid; i < 96*32; i += 256) Wv[i] = lin_vec_w[i];
  __syncthreads();
  const int grp = tid >> 5;
  const int m   = tid & 31;
  const int e   = blockIdx.x*8 + grp;
  float* wrow = out + (size_t)e*OUT_D;

  float4 x   = *(const float4*)(eq_feat + ((size_t)e*32 + m)*4);
  float2 w01 = *(const float2*)(wrow + 256 + 2*m);
  float sw = x.x*w01.x, v0 = x.y*w01.y, v1 = x.z*w01.y, v2 = x.w*w01.y;
  const int nidx = ctr[e];
  float4 evv = *(const float4*)(env2 + (size_t)nidx*128 + m*4);

  float ps_ = sw*sw, pv_ = v0*v0 + v1*v1 + v2*v2;
  #pragma unroll
  for (int off=16; off; off>>=1) {
    ps_ += __shfl_xor(ps_, off, 32);
    pv_ += __shfl_xor(pv_, off, 32);
  }
  float inv_s = rsqrtf(ps_*(1.f/32.f)+EPS6);
  float inv_v = rsqrtf(pv_*(1.f/96.f)+EPS6);
  float s  = sw*inv_s*eq_norm_w[2*m];
  float fv = inv_v*eq_norm_w[2*m+1];
  v0 *= fv; v1 *= fv; v2 *= fv;
  float es = evv.x, e0 = evv.y, e1 = evv.z, e2 = evv.w;
  float os0 = s*es;
  float os1 = (v0*e0 + v1*e1 + v2*e2) * 0.5773502691896258f;
  float a00=s*e0, a01=s*e1, a02=s*e2;
  float a10=v0*es, a11=v1*es, a12=v2*es;
  const float is2 = 0.7071067811865476f;
  float a20=(v1*e2 - v2*e1)*is2;
  float a21=(v2*e0 - v0*e2)*is2;
  float a22=(v0*e1 - v1*e0)*is2;
  float q0 = os0*os0, q1 = os1*os1;
  float q2 = a00*a00+a01*a01+a02*a02;
  float q3 = a10*a10+a11*a11+a12*a12;
  float q4 = a20*a20+a21*a21+a22*a22;
  #pragma unroll
  for (int off=16; off; off>>=1) {
    q0 += __shfl_xor(q0, off, 32); q1 += __shfl_xor(q1, off, 32);
    q2 += __shfl_xor(q2, off, 32); q3 += __shfl_xor(q3, off, 32);
    q4 += __shfl_xor(q4, off, 32);
  }
  float t0 = rsqrtf(q0*(1.f/32.f)+EPS6)*tp_norm_w[m*5+0];
  float t1 = rsqrtf(q1*(1.f/32.f)+EPS6)*tp_norm_w[m*5+1];
  float f0 = rsqrtf(q2*(1.f/96.f)+EPS6)*tp_norm_w[m*5+2];
  float f1 = rsqrtf(q3*(1.f/96.f)+EPS6)*tp_norm_w[m*5+3];
  float f2 = rsqrtf(q4*(1.f/96.f)+EPS6)*tp_norm_w[m*5+4];

  *(float2*)(wrow + 256 + 2*m) = make_float2(os0*t0, os1*t1);
  ov[grp][3*m+0][0]=a00*f0; ov[grp][3*m+0][1]=a01*f0; ov[grp][3*m+0][2]=a02*f0;
  ov[grp][3*m+1][0]=a10*f1; ov[grp][3*m+1][1]=a11*f1; ov[grp][3*m+1][2]=a12*f1;
  ov[grp][3*m+2][0]=a20*f2; ov[grp][3*m+2][1]=a21*f2; ov[grp][3*m+2][2]=a22*f2;
  float acc0=0.f, acc1=0.f, acc2=0.f;
  #pragma unroll 4
  for (int i=0;i<96;++i) {
    float wv = Wv[i*32 + m];
    acc0 += ov[grp][i][0]*wv;
    acc1 += ov[grp][i][1]*wv;
    acc2 += ov[grp][i][2]*wv;
  }
  wrow[320 + 3*m + 0] = acc0;
  wrow[320 + 3*m + 1] = acc1;
  wrow[320 + 3*m + 2] = acc2;
}

// =============================================================================
extern "C" void kernel_launch(void* const* d_in, const int* in_sizes, int n_in,
                              void* d_out, int out_size, void* d_ws, size_t ws_size,
                              hipStream_t stream)
{
  (void)in_sizes; (void)n_in; (void)out_size; (void)ws_size;
  const float* x      = (const float*)d_in[0];
  const float* cut    = (const float*)d_in[1];
  const float* eqf    = (const float*)d_in[2];
  const float* eattr  = (const float*)d_in[3];
  const float* ninv   = (const float*)d_in[4];
  const float* einv   = (const float*)d_in[5];
  const float* W1     = (const float*)d_in[6];
  const float* b1     = (const float*)d_in[7];
  const float* W2     = (const float*)d_in[8];
  const float* b2     = (const float*)d_in[9];
  const float* ln_g   = (const float*)d_in[10];
  const float* ln_b   = (const float*)d_in[11];
  const float* We1    = (const float*)d_in[12];
  const float* be1    = (const float*)d_in[13];
  const float* We2    = (const float*)d_in[14];
  const float* be2    = (const float*)d_in[15];
  const float* Wq     = (const float*)d_in[16];
  const float* Wk     = (const float*)d_in[17];
  const float* eq_nw  = (const float*)d_in[18];
  const float* env_nw = (const float*)d_in[19];
  const float* env_lw = (const float*)d_in[20];
  const float* tp_nw  = (const float*)d_in[21];
  const float* lin_vw = (const float*)d_in[22];
  const int*   ctr    = (const int*)d_in[23];
  const int*   nbr    = (const int*)d_in[24];

  float* out = (float*)d_out;
  float* ws  = (float*)d_ws;
  ushort* Hhi   = (ushort*)(ws + WS_H);     // E x 256 bf16 hi (G1 out, then G3 out hi)
  ushort* Hlo   = (ushort*)(ws + WS_QK);    // E x 256 bf16 lo (G1 out, then G3 out lo)
  float* Qb     = ws + WS_QK;               // reuses lo region after G4
  float* Kb     = Qb + (size_t)QK_CH*512;
  float* att    = ws + WS_ATT;
  float* env2   = ws + WS_ENV2;
  int* cnt      = (int*)(ws + WS_CNT);
  int* rowptr   = (int*)(ws + WS_ROWPTR);
  int* cursor   = (int*)(ws + WS_CURSOR);
  int* eidx     = (int*)(ws + WS_EIDX);
  ushort* WB    = (ushort*)(ws + WS_WB);

  // zero the degree histogram only (32 KB)
  hipMemsetAsync(cnt, 0, N_NODES*sizeof(int), stream);

  // CSR build (independent of GEMM chain; cheap)
  hist_kernel<<<E_EDGES/256, 256, 0, stream>>>(ctr, cnt);
  scan_kernel<<<1, 256, 0, stream>>>(cnt, rowptr, cursor);
  scatter_kernel<<<E_EDGES/256, 256, 0, stream>>>(ctr, cursor, eidx);

  // weight conversion (transposed, zero-padded rows, hi/lo planes)
  wconv_kernel<<<192, 256, 0, stream>>>(W1,  WB+WB_W1H,  WB+WB_W1L,  192, 256, 256);
  wconv_kernel<<<256, 256, 0, stream>>>(W2,  WB+WB_W2H,  WB+WB_W2L,  256, 256, 256);
  wconv_kernel<<<256, 256, 0, stream>>>(We1, WB+WB_WE1H, WB+WB_WE1L, 256, 256, 256);
  wconv_kernel<<<192, 256, 0, stream>>>(We2, WB+WB_WE2H, WB+WB_WE2L, 256, 160, 192);
  wconv_kernel<<<384, 256, 0, stream>>>(Wq,  WB+WB_WQH,  WB+WB_WQL,  192, 512, 512);
  wconv_kernel<<<512, 256, 0, stream>>>(Wk,  WB+WB_WKH,  WB+WB_WKL,  256, 512, 512);

  dim3 blk(256);
  // G1 (split): silu(x @ W1 + b1) -> H hi/lo
  mfma_gemm<1,0,2><<<dim3(4, E_EDGES/128), blk, 0, stream>>>(
      x, nullptr, D_INF, WB+WB_W1H, WB+WB_W1L, 192, b1,
      Hhi, Hlo, 256, 256, nullptr,nullptr,nullptr,nullptr,0);
  // G2 (split): H @ W2 + b2 -> d_out cols 0..255 (f32)
  mfma_gemm<0,3,0><<<dim3(4, E_EDGES/128), blk, 0, stream>>>(
      Hhi, Hlo, 256, WB+WB_W2H, WB+WB_W2L, 256, b2,
      out, nullptr, OUT_D, 256, nullptr,nullptr,nullptr,nullptr,0);
  // LayerNorm + cutoff (f32, in place)
  ln_cutoff_kernel<<<E_EDGES, 256, 0, stream>>>(out, ln_g, ln_b, cut);
  // G3 (split): silu(lat @ We1 + be1) -> H2 hi/lo (reuses H regions)
  mfma_gemm<1,0,2><<<dim3(4, E_EDGES/128), blk, 0, stream>>>(
      out, nullptr, OUT_D, WB+WB_WE1H, WB+WB_WE1L, 256, be1,
      Hhi, Hlo, 256, 256, nullptr,nullptr,nullptr,nullptr,0);
  // G4 (split): H2 @ We2 + be2 -> d_out cols 256..415 (f32)
  mfma_gemm<0,3,0><<<dim3(3, E_EDGES/128), blk, 0, stream>>>(
      Hhi, Hlo, 256, WB+WB_WE2H, WB+WB_WE2L, 256, be2,
      out + 256, nullptr, OUT_D, 160, nullptr,nullptr,nullptr,nullptr,0);
  // QK phase (split), chunked through retired Hlo region
  for (int c = 0; c < E_EDGES/QK_CH; ++c) {
    const int e0 = c * QK_CH;
    mfma_gemm<0,2,0><<<dim3(8, QK_CH/128), blk, 0, stream>>>(
        nullptr, nullptr, 0, WB+WB_WQH, WB+WB_WQL, 192, nullptr,
        Qb, nullptr, 512, 512, ninv, einv, ctr, nbr, e0);
    mfma_gemm<0,0,0><<<dim3(8, QK_CH/128), blk, 0, stream>>>(
        out + (size_t)e0*OUT_D, nullptr, OUT_D, WB+WB_WKH, WB+WB_WKL, 256, nullptr,
        Kb, nullptr, 512, 512, nullptr,nullptr,nullptr,nullptr,0);
    qk_dot_kernel<<<(QK_CH*32)/256, 256, 0, stream>>>(Qb, Kb, att, e0);
  }
  // fused per-node softmax + env + norm + mixing
  node_env_kernel<<<N_NODES, 128, 0, stream>>>(att, eidx, rowptr, eattr, out,
                                               env_nw, env_lw, env2);
  // final per-edge tensor product
  edge_final_kernel<<<E_EDGES/8, 256, 0, stream>>>(eqf, env2, ctr, eq_nw, tp_nw, lin_vw, out);
}

// Round 6
// 951.412 us; speedup vs baseline: 2.6057x; 1.3706x over previous
//
#include <hip/hip_runtime.h>
#include <cstddef>
#include <cstdint>

// Problem constants (fixed by setup_inputs)
#define E_EDGES 131072
#define N_NODES 8192
#define D_INF   192
#define L_DIM   256
#define OUT_D   416
#define EPS6    1e-6f
#define GA      40            // LDS row stride (shorts): 80B rows -> 2-way-max banks

// ws layout (float offsets)
#define WS_HHI   0ull          // E*256 bf16 hi plane (G1/G3 out)
#define WS_HLO   16777216ull   // E*256 bf16 lo plane
#define WS_ATT   33554432ull   // E*32 f32 logits
#define WS_ENV2  37748736ull   // N*128 f32
#define WS_CNT   38797312ull   // N int
#define WS_ROWPTR 38805504ull  // N+1 int (padded)
#define WS_CURSOR 38813760ull  // N int
#define WS_EIDX  38821952ull   // E int
#define WS_WB    38953024ull   // bf16 weight planes

// WB ushort offsets (hi/lo pairs; transposed (N,K) row-major)
#define WB_W1H   0
#define WB_W1L   49152
#define WB_W2H   98304
#define WB_W2L   163840
#define WB_WE1H  229376
#define WB_WE1L  294912
#define WB_WE2H  360448
#define WB_WE2L  401408
#define WB_WQH   442368
#define WB_WQL   540672
#define WB_WKH   638976
#define WB_WKL   770048

typedef __attribute__((ext_vector_type(8))) short bf16x8;
typedef __attribute__((ext_vector_type(4))) float f32x4;

__device__ __forceinline__ ushort f2bf(float f){
  unsigned u = __float_as_uint(f);
  unsigned r = u + 0x7fffu + ((u>>16)&1u);
  return (ushort)(r>>16);
}
__device__ __forceinline__ float bf2f(ushort h){
  return __uint_as_float(((unsigned)h)<<16);
}
__device__ __forceinline__ void split2(float v, ushort &h, ushort &l){
  h = f2bf(v);
  l = f2bf(v - bf2f(h));
}

// ---------------- weight transpose+convert: Wt[n][k] = bf16(W[k][n]) --------
__global__ __launch_bounds__(256) void wconv_kernel(
    const float* __restrict__ W, ushort* __restrict__ Whi,
    ushort* __restrict__ Wlo, int K, int N)
{
  int idx = blockIdx.x*256 + threadIdx.x;
  if (idx >= N*K) return;
  int n = idx / K, k = idx - n*K;
  float v = W[(size_t)k*N + n];
  ushort h = f2bf(v);
  Whi[idx] = h;
  Wlo[idx] = f2bf(v - bf2f(h));
}

// ---------------- wide split-bf16 MFMA GEMM: full-N per block ----------------
// BM=128, BN=32*WNT (per wave: WNT 16-col tiles), BK=32, 4 waves (2x2).
// AMODE: 0 = A f32 row-major (split on the fly), 3 = A bf16 hi/lo pair
// OMODE: 0 = f32 C, 2 = bf16 hi/lo pair C
// LNEPI: fused LayerNorm(+bias)+cutoff epilogue (G2), writes f32 C
template<int ACT, int AMODE, int OMODE, int WNT, int LNEPI>
__global__ __launch_bounds__(256,2) void gemm_wide(
    const void* __restrict__ Aptr, const void* __restrict__ Aptr2, int lda,
    const ushort* __restrict__ Bhi, const ushort* __restrict__ Blo, int Kdim,
    const float* __restrict__ bias,
    void* __restrict__ Cptr, void* __restrict__ Cptr2, int ldc,
    const float* __restrict__ lng, const float* __restrict__ lnb,
    const float* __restrict__ cut)
{
  constexpr int BN = 32*WNT;
  __shared__ ushort As[2][128][GA];
  __shared__ ushort Bs[2][BN][GA];
  __shared__ float sbuf[128][2];
  __shared__ float qbuf[128][2];
  const int tid  = threadIdx.x;
  const int row0 = blockIdx.x * 128;
  const int srow = tid >> 2;          // 0..63
  const int skc  = (tid & 3) * 8;     // 0,8,16,24
  const int w    = tid >> 6, lane = tid & 63;
  const int wm   = w >> 1,  wn   = w & 1;
  const int lr   = lane & 15, kg = lane >> 4;

  f32x4 acc[4][WNT];
  #pragma unroll
  for (int mi=0;mi<4;++mi)
    #pragma unroll
    for (int ni=0;ni<WNT;++ni) acc[mi][ni] = (f32x4){0.f,0.f,0.f,0.f};

  for (int k0 = 0; k0 < Kdim; k0 += 32) {
    #pragma unroll
    for (int br = srow; br < BN; br += 64) {
      *(bf16x8*)&Bs[0][br][skc] = *(const bf16x8*)(Bhi + (size_t)br*Kdim + k0 + skc);
      *(bf16x8*)&Bs[1][br][skc] = *(const bf16x8*)(Blo + (size_t)br*Kdim + k0 + skc);
    }
    #pragma unroll
    for (int rep = 0; rep < 2; ++rep) {
      const int row = rep*64 + srow;
      if (AMODE == 3) {
        const size_t off = (size_t)(row0+row)*lda + k0 + skc;
        *(bf16x8*)&As[0][row][skc] = *(const bf16x8*)((const ushort*)Aptr + off);
        *(bf16x8*)&As[1][row][skc] = *(const bf16x8*)((const ushort*)Aptr2 + off);
      } else {
        const float* ap = (const float*)Aptr + (size_t)(row0+row)*lda + k0 + skc;
        float4 f0 = *(const float4*)ap;
        float4 f1 = *(const float4*)(ap+4);
        float vs[8] = {f0.x,f0.y,f0.z,f0.w,f1.x,f1.y,f1.z,f1.w};
        union { ushort u[8]; bf16x8 v; } th, tl;
        #pragma unroll
        for (int j=0;j<8;++j) split2(vs[j], th.u[j], tl.u[j]);
        *(bf16x8*)&As[0][row][skc] = th.v;
        *(bf16x8*)&As[1][row][skc] = tl.v;
      }
    }
    __syncthreads();
    bf16x8 ah[4], al[4];
    #pragma unroll
    for (int mi=0;mi<4;++mi) {
      ah[mi] = *(const bf16x8*)&As[0][wm*64 + mi*16 + lr][kg*8];
      al[mi] = *(const bf16x8*)&As[1][wm*64 + mi*16 + lr][kg*8];
    }
    #pragma unroll
    for (int ni=0;ni<WNT;++ni) {
      const int bro = wn*(16*WNT) + ni*16 + lr;
      bf16x8 bh = *(const bf16x8*)&Bs[0][bro][kg*8];
      bf16x8 bl = *(const bf16x8*)&Bs[1][bro][kg*8];
      #pragma unroll
      for (int mi=0;mi<4;++mi) {
        acc[mi][ni] = __builtin_amdgcn_mfma_f32_16x16x32_bf16(al[mi], bh, acc[mi][ni], 0, 0, 0);
        acc[mi][ni] = __builtin_amdgcn_mfma_f32_16x16x32_bf16(ah[mi], bl, acc[mi][ni], 0, 0, 0);
        acc[mi][ni] = __builtin_amdgcn_mfma_f32_16x16x32_bf16(ah[mi], bh, acc[mi][ni], 0, 0, 0);
      }
    }
    __syncthreads();
  }

  if (!LNEPI) {
    #pragma unroll
    for (int ni=0;ni<WNT;++ni) {
      const int col = wn*(16*WNT) + ni*16 + lr;
      const float bv = bias[col];
      #pragma unroll
      for (int mi=0;mi<4;++mi) {
        #pragma unroll
        for (int r=0;r<4;++r) {
          const int row = row0 + wm*64 + mi*16 + kg*4 + r;
          float v = acc[mi][ni][r] + bv;
          if (ACT == 1) v = v / (1.f + __expf(-v));
          const size_t oidx = (size_t)row*ldc + col;
          if (OMODE == 0) ((float*)Cptr)[oidx] = v;
          else {
            ushort h, l; split2(v, h, l);
            ((ushort*)Cptr)[oidx]  = h;
            ((ushort*)Cptr2)[oidx] = l;
          }
        }
      }
    }
  } else {
    // fused bias + LayerNorm + cutoff epilogue (row = full 256 cols in block)
    float bsv[WNT], gvv[WNT], bvv[WNT];
    #pragma unroll
    for (int ni=0;ni<WNT;++ni) {
      const int col = wn*(16*WNT) + ni*16 + lr;
      bsv[ni] = bias[col]; gvv[ni] = lng[col]; bvv[ni] = lnb[col];
    }
    #pragma unroll
    for (int mi=0;mi<4;++mi) {
      #pragma unroll
      for (int r=0;r<4;++r) {
        float s = 0.f, q = 0.f;
        #pragma unroll
        for (int ni=0;ni<WNT;++ni) {
          float v = acc[mi][ni][r] + bsv[ni];
          acc[mi][ni][r] = v;
          s += v; q += v*v;
        }
        s += __shfl_xor(s, 1); q += __shfl_xor(q, 1);
        s += __shfl_xor(s, 2); q += __shfl_xor(q, 2);
        s += __shfl_xor(s, 4); q += __shfl_xor(q, 4);
        s += __shfl_xor(s, 8); q += __shfl_xor(q, 8);
        if (lr == 0) {
          const int rl = wm*64 + mi*16 + kg*4 + r;
          sbuf[rl][wn] = s; qbuf[rl][wn] = q;
        }
      }
    }
    __syncthreads();
    #pragma unroll
    for (int mi=0;mi<4;++mi) {
      #pragma unroll
      for (int r=0;r<4;++r) {
        const int rl = wm*64 + mi*16 + kg*4 + r;
        const float S = sbuf[rl][0] + sbuf[rl][1];
        const float Q = qbuf[rl][0] + qbuf[rl][1];
        const float mean = S * (1.f/256.f);
        const float var  = Q * (1.f/256.f) - mean*mean;
        const float rs   = rsqrtf(var + 1e-5f);
        const float cutv = cut[row0 + rl];
        #pragma unroll
        for (int ni=0;ni<WNT;++ni) {
          const int col = wn*(16*WNT) + ni*16 + lr;
          float nv = (acc[mi][ni][r] - mean)*rs*gvv[ni] + bvv[ni];
          if (col < 128) nv *= cutv;
          ((float*)Cptr)[(size_t)(row0 + rl)*ldc + col] = nv;
        }
      }
    }
  }
}

// ---------------- fused QK attention logits: att[e,m] = 4 * sum_d Q*K -------
// Per block: 128 edges. Loop n0 over 512 cols; Q,K tiles live in registers only.
__global__ __launch_bounds__(256,2) void qk_att_kernel(
    const float* __restrict__ out, const float* __restrict__ ninv,
    const float* __restrict__ einv,
    const int* __restrict__ ctr, const int* __restrict__ nbr,
    const ushort* __restrict__ Wqh, const ushort* __restrict__ Wql,
    const ushort* __restrict__ Wkh, const ushort* __restrict__ Wkl,
    float* __restrict__ att)
{
  __shared__ ushort As[2][128][GA];
  __shared__ ushort Bs[2][64][GA];
  const int tid  = threadIdx.x;
  const int row0 = blockIdx.x * 128;
  const int srow = tid >> 2;
  const int skc  = (tid & 3) * 8;
  const int w    = tid >> 6, lane = tid & 63;
  const int wm   = w >> 1,  wn   = w & 1;
  const int lr   = lane & 15, kg = lane >> 4;
  // hoist gather indices (rows srow and 64+srow of this block)
  const int cA = ctr[row0 + srow],      nA = nbr[row0 + srow];
  const int cB = ctr[row0 + 64 + srow], nB = nbr[row0 + 64 + srow];

  for (int n0 = 0; n0 < 512; n0 += 64) {
    // ---- Q tile (cols n0..n0+63), K-dim 192, efa gather ----
    f32x4 accQ[4][2];
    #pragma unroll
    for (int mi=0;mi<4;++mi){ accQ[mi][0]=(f32x4){0,0,0,0}; accQ[mi][1]=(f32x4){0,0,0,0}; }
    for (int k0 = 0; k0 < 192; k0 += 32) {
      *(bf16x8*)&Bs[0][srow][skc] = *(const bf16x8*)(Wqh + (size_t)(n0+srow)*192 + k0 + skc);
      *(bf16x8*)&Bs[1][srow][skc] = *(const bf16x8*)(Wql + (size_t)(n0+srow)*192 + k0 + skc);
      #pragma unroll
      for (int rep=0; rep<2; ++rep) {
        const int row = rep*64 + srow;
        const int e = row0 + row;
        const int ci = rep ? cB : cA, nn = rep ? nB : nA;
        const int k = k0 + skc;
        const float* ap;
        if (k < 64)        ap = ninv + (size_t)ci*64 + k;
        else if (k < 128)  ap = ninv + (size_t)nn*64 + (k-64);
        else               ap = einv + (size_t)e*64 + (k-128);
        float4 f0 = *(const float4*)ap;
        float4 f1 = *(const float4*)(ap+4);
        float vs[8] = {f0.x,f0.y,f0.z,f0.w,f1.x,f1.y,f1.z,f1.w};
        union { ushort u[8]; bf16x8 v; } th, tl;
        #pragma unroll
        for (int j=0;j<8;++j) split2(vs[j], th.u[j], tl.u[j]);
        *(bf16x8*)&As[0][row][skc] = th.v;
        *(bf16x8*)&As[1][row][skc] = tl.v;
      }
      __syncthreads();
      bf16x8 ah[4], al[4];
      #pragma unroll
      for (int mi=0;mi<4;++mi) {
        ah[mi] = *(const bf16x8*)&As[0][wm*64 + mi*16 + lr][kg*8];
        al[mi] = *(const bf16x8*)&As[1][wm*64 + mi*16 + lr][kg*8];
      }
      #pragma unroll
      for (int ni=0;ni<2;++ni) {
        const int bro = wn*32 + ni*16 + lr;
        bf16x8 bh = *(const bf16x8*)&Bs[0][bro][kg*8];
        bf16x8 bl = *(const bf16x8*)&Bs[1][bro][kg*8];
        #pragma unroll
        for (int mi=0;mi<4;++mi) {
          accQ[mi][ni] = __builtin_amdgcn_mfma_f32_16x16x32_bf16(al[mi], bh, accQ[mi][ni], 0, 0, 0);
          accQ[mi][ni] = __builtin_amdgcn_mfma_f32_16x16x32_bf16(ah[mi], bl, accQ[mi][ni], 0, 0, 0);
          accQ[mi][ni] = __builtin_amdgcn_mfma_f32_16x16x32_bf16(ah[mi], bh, accQ[mi][ni], 0, 0, 0);
        }
      }
      __syncthreads();
    }
    // ---- K tile (cols n0..n0+63), K-dim 256, latents from out ----
    f32x4 accK[4][2];
    #pragma unroll
    for (int mi=0;mi<4;++mi){ accK[mi][0]=(f32x4){0,0,0,0}; accK[mi][1]=(f32x4){0,0,0,0}; }
    for (int k0 = 0; k0 < 256; k0 += 32) {
      *(bf16x8*)&Bs[0][srow][skc] = *(const bf16x8*)(Wkh + (size_t)(n0+srow)*256 + k0 + skc);
      *(bf16x8*)&Bs[1][srow][skc] = *(const bf16x8*)(Wkl + (size_t)(n0+srow)*256 + k0 + skc);
      #pragma unroll
      for (int rep=0; rep<2; ++rep) {
        const int row = rep*64 + srow;
        const float* ap = out + (size_t)(row0+row)*OUT_D + k0 + skc;
        float4 f0 = *(const float4*)ap;
        float4 f1 = *(const float4*)(ap+4);
        float vs[8] = {f0.x,f0.y,f0.z,f0.w,f1.x,f1.y,f1.z,f1.w};
        union { ushort u[8]; bf16x8 v; } th, tl;
        #pragma unroll
        for (int j=0;j<8;++j) split2(vs[j], th.u[j], tl.u[j]);
        *(bf16x8*)&As[0][row][skc] = th.v;
        *(bf16x8*)&As[1][row][skc] = tl.v;
      }
      __syncthreads();
      bf16x8 ah[4], al[4];
      #pragma unroll
      for (int mi=0;mi<4;++mi) {
        ah[mi] = *(const bf16x8*)&As[0][wm*64 + mi*16 + lr][kg*8];
        al[mi] = *(const bf16x8*)&As[1][wm*64 + mi*16 + lr][kg*8];
      }
      #pragma unroll
      for (int ni=0;ni<2;++ni) {
        const int bro = wn*32 + ni*16 + lr;
        bf16x8 bh = *(const bf16x8*)&Bs[0][bro][kg*8];
        bf16x8 bl = *(const bf16x8*)&Bs[1][bro][kg*8];
        #pragma unroll
        for (int mi=0;mi<4;++mi) {
          accK[mi][ni] = __builtin_amdgcn_mfma_f32_16x16x32_bf16(al[mi], bh, accK[mi][ni], 0, 0, 0);
          accK[mi][ni] = __builtin_amdgcn_mfma_f32_16x16x32_bf16(ah[mi], bl, accK[mi][ni], 0, 0, 0);
          accK[mi][ni] = __builtin_amdgcn_mfma_f32_16x16x32_bf16(ah[mi], bh, accK[mi][ni], 0, 0, 0);
        }
      }
      __syncthreads();
    }
    // ---- elementwise product + 16-lane d-reduction -> att ----
    #pragma unroll
    for (int mi=0;mi<4;++mi) {
      #pragma unroll
      for (int ni=0;ni<2;++ni) {
        float p[4];
        #pragma unroll
        for (int r=0;r<4;++r) p[r] = accQ[mi][ni][r]*accK[mi][ni][r];
        #pragma unroll
        for (int r=0;r<4;++r) {
          p[r] += __shfl_xor(p[r], 1);
          p[r] += __shfl_xor(p[r], 2);
          p[r] += __shfl_xor(p[r], 4);
          p[r] += __shfl_xor(p[r], 8);
        }
        if (lr == 0) {
          const int m = (n0 >> 4) + wn*2 + ni;
          #pragma unroll
          for (int r=0;r<4;++r) {
            const int row = wm*64 + mi*16 + kg*4 + r;
            att[(size_t)(row0+row)*32 + m] = 4.0f * p[r];
          }
        }
      }
    }
  }
}

// ---------------- CSR build: histogram / scan / scatter ---------------------
__global__ __launch_bounds__(256) void hist_kernel(
    const int* __restrict__ ctr, int* __restrict__ cnt)
{
  int e = blockIdx.x*256 + threadIdx.x;
  if (e < E_EDGES) atomicAdd(&cnt[ctr[e]], 1);
}

__global__ __launch_bounds__(256) void scan_kernel(
    const int* __restrict__ cnt, int* __restrict__ rowptr,
    int* __restrict__ cursor)
{
  __shared__ int part[256];
  const int t = threadIdx.x;
  const int base = t*32;
  int local[32];
  int s = 0;
  #pragma unroll
  for (int k=0;k<32;++k){ local[k]=cnt[base+k]; s+=local[k]; }
  part[t]=s; __syncthreads();
  for (int off=1; off<256; off<<=1){
    int v = (t>=off)? part[t-off] : 0;
    __syncthreads();
    part[t]+=v;
    __syncthreads();
  }
  int run = (t==0)?0:part[t-1];
  #pragma unroll
  for (int k=0;k<32;++k){ rowptr[base+k]=run; cursor[base+k]=run; run+=local[k]; }
  if (t==255) rowptr[N_NODES]=run;
}

__global__ __launch_bounds__(256) void scatter_kernel(
    const int* __restrict__ ctr, int* __restrict__ cursor,
    int* __restrict__ eidx)
{
  int e = blockIdx.x*256 + threadIdx.x;
  if (e < E_EDGES){ int p = atomicAdd(&cursor[ctr[e]],1); eidx[p]=e; }
}

// ---------------- fused per-node: softmax + env accum + so3_norm + mixing ---
__global__ __launch_bounds__(128) void node_env_kernel(
    const float* __restrict__ att, const int* __restrict__ eidx,
    const int* __restrict__ rowptr, const float* __restrict__ eattr,
    const float* __restrict__ outbuf,
    const float* __restrict__ env_nw, const float* __restrict__ env_lw,
    float* __restrict__ env2)
{
  __shared__ float mx_s[32], rs_s[32];
  __shared__ float jm[4][32], js[4][32];
  __shared__ float ev[128];
  __shared__ float2 red[128];
  const int n = blockIdx.x, t = threadIdx.x;
  const int start = rowptr[n], deg = rowptr[n+1] - start;
  {
    const int m = t & 31, j = t >> 5;
    float lm = -3.4e38f, ls = 0.f;
    for (int i = j; i < deg; i += 4) {
      float l = att[(size_t)eidx[start+i]*32 + m];
      if (l > lm) { ls = ls * __expf(lm - l) + 1.f; lm = l; }
      else ls += __expf(l - lm);
    }
    jm[j][m] = lm; js[j][m] = ls;
  }
  __syncthreads();
  if (t < 32) {
    const int m = t;
    float M = jm[0][m];
    #pragma unroll
    for (int q=1;q<4;++q) M = fmaxf(M, jm[q][m]);
    float S = 0.f;
    #pragma unroll
    for (int q=0;q<4;++q) S += js[q][m] * __expf(jm[q][m] - M);
    mx_s[m] = M;
    rs_s[m] = 1.f / (S + 1e-16f);
  }
  __syncthreads();
  const int m2 = t >> 2, d = t & 3;
  const float M2 = mx_s[m2], R2 = rs_s[m2];
  float acc = 0.f;
  for (int i = 0; i < deg; ++i) {
    const int e = eidx[start+i];
    float a = __expf(att[(size_t)e*32 + m2] - M2) * R2;
    const float* wr = outbuf + (size_t)e*OUT_D + 256;
    float w = (d==0) ? wr[64 + 2*m2] : wr[65 + 2*m2];
    float sc = wr[128 + m2];
    float ea = eattr[(size_t)e*128 + m2*4 + d];
    acc += ea * w * sc * a;
  }
  float val = acc;
  red[t] = make_float2(d==0 ? val*val : 0.f, d!=0 ? val*val : 0.f);
  __syncthreads();
  for (int off=64; off>0; off>>=1) {
    if (t<off){ red[t].x += red[t+off].x; red[t].y += red[t+off].y; }
    __syncthreads();
  }
  float inv_s = rsqrtf(red[0].x*(1.f/32.f)+EPS6);
  float inv_v = rsqrtf(red[0].y*(1.f/96.f)+EPS6);
  float nv = (d==0) ? val*inv_s*env_nw[2*m2] : val*inv_v*env_nw[2*m2+1];
  ev[t] = nv;
  __syncthreads();
  const float* WL = env_lw + (d==0 ? 0 : 1024);
  float a2 = 0.f;
  #pragma unroll 8
  for (int q=0;q<32;++q) a2 += ev[q*4+d]*WL[q*32+m2];
  env2[(size_t)n*128 + m2*4 + d] = a2;
}

// ---------------- per-edge tensor product: 32 lanes/edge, 8 edges/block -----
__global__ __launch_bounds__(256) void edge_final_kernel(
    const float* __restrict__ eq_feat, const float* __restrict__ env2,
    const int* __restrict__ ctr,
    const float* __restrict__ eq_norm_w, const float* __restrict__ tp_norm_w,
    const float* __restrict__ lin_vec_w, float* __restrict__ out)
{
  __shared__ float Wv[96*32];
  __shared__ float ov[8][96][3];
  const int tid = threadIdx.x;
  for (int i = tid; i < 96*32; i += 256) Wv[i] = lin_vec_w[i];
  __syncthreads();
  const int grp = tid >> 5;
  const int m   = tid & 31;
  const int e   = blockIdx.x*8 + grp;
  float* wrow = out + (size_t)e*OUT_D;

  float4 x   = *(const float4*)(eq_feat + ((size_t)e*32 + m)*4);
  float2 w01 = *(const float2*)(wrow + 256 + 2*m);
  float sw = x.x*w01.x, v0 = x.y*w01.y, v1 = x.z*w01.y, v2 = x.w*w01.y;
  const int nidx = ctr[e];
  float4 evv = *(const float4*)(env2 + (size_t)nidx*128 + m*4);

  float ps_ = sw*sw, pv_ = v0*v0 + v1*v1 + v2*v2;
  #pragma unroll
  for (int off=16; off; off>>=1) {
    ps_ += __shfl_xor(ps_, off, 32);
    pv_ += __shfl_xor(pv_, off, 32);
  }
  float inv_s = rsqrtf(ps_*(1.f/32.f)+EPS6);
  float inv_v = rsqrtf(pv_*(1.f/96.f)+EPS6);
  float s  = sw*inv_s*eq_norm_w[2*m];
  float fv = inv_v*eq_norm_w[2*m+1];
  v0 *= fv; v1 *= fv; v2 *= fv;
  float es = evv.x, e0 = evv.y, e1 = evv.z, e2 = evv.w;
  float os0 = s*es;
  float os1 = (v0*e0 + v1*e1 + v2*e2) * 0.5773502691896258f;
  float a00=s*e0, a01=s*e1, a02=s*e2;
  float a10=v0*es, a11=v1*es, a12=v2*es;
  const float is2 = 0.7071067811865476f;
  float a20=(v1*e2 - v2*e1)*is2;
  float a21=(v2*e0 - v0*e2)*is2;
  float a22=(v0*e1 - v1*e0)*is2;
  float q0 = os0*os0, q1 = os1*os1;
  float q2 = a00*a00+a01*a01+a02*a02;
  float q3 = a10*a10+a11*a11+a12*a12;
  float q4 = a20*a20+a21*a21+a22*a22;
  #pragma unroll
  for (int off=16; off; off>>=1) {
    q0 += __shfl_xor(q0, off, 32); q1 += __shfl_xor(q1, off, 32);
    q2 += __shfl_xor(q2, off, 32); q3 += __shfl_xor(q3, off, 32);
    q4 += __shfl_xor(q4, off, 32);
  }
  float t0 = rsqrtf(q0*(1.f/32.f)+EPS6)*tp_norm_w[m*5+0];
  float t1 = rsqrtf(q1*(1.f/32.f)+EPS6)*tp_norm_w[m*5+1];
  float f0 = rsqrtf(q2*(1.f/96.f)+EPS6)*tp_norm_w[m*5+2];
  float f1 = rsqrtf(q3*(1.f/96.f)+EPS6)*tp_norm_w[m*5+3];
  float f2 = rsqrtf(q4*(1.f/96.f)+EPS6)*tp_norm_w[m*5+4];

  *(float2*)(wrow + 256 + 2*m) = make_float2(os0*t0, os1*t1);
  ov[grp][3*m+0][0]=a00*f0; ov[grp][3*m+0][1]=a01*f0; ov[grp][3*m+0][2]=a02*f0;
  ov[grp][3*m+1][0]=a10*f1; ov[grp][3*m+1][1]=a11*f1; ov[grp][3*m+1][2]=a12*f1;
  ov[grp][3*m+2][0]=a20*f2; ov[grp][3*m+2][1]=a21*f2; ov[grp][3*m+2][2]=a22*f2;
  float acc0=0.f, acc1=0.f, acc2=0.f;
  #pragma unroll 4
  for (int i=0;i<96;++i) {
    float wv = Wv[i*32 + m];
    acc0 += ov[grp][i][0]*wv;
    acc1 += ov[grp][i][1]*wv;
    acc2 += ov[grp][i][2]*wv;
  }
  wrow[320 + 3*m + 0] = acc0;
  wrow[320 + 3*m + 1] = acc1;
  wrow[320 + 3*m + 2] = acc2;
}

// =============================================================================
extern "C" void kernel_launch(void* const* d_in, const int* in_sizes, int n_in,
                              void* d_out, int out_size, void* d_ws, size_t ws_size,
                              hipStream_t stream)
{
  (void)in_sizes; (void)n_in; (void)out_size; (void)ws_size;
  const float* x      = (const float*)d_in[0];
  const float* cut    = (const float*)d_in[1];
  const float* eqf    = (const float*)d_in[2];
  const float* eattr  = (const float*)d_in[3];
  const float* ninv   = (const float*)d_in[4];
  const float* einv   = (const float*)d_in[5];
  const float* W1     = (const float*)d_in[6];
  const float* b1     = (const float*)d_in[7];
  const float* W2     = (const float*)d_in[8];
  const float* b2     = (const float*)d_in[9];
  const float* ln_g   = (const float*)d_in[10];
  const float* ln_b   = (const float*)d_in[11];
  const float* We1    = (const float*)d_in[12];
  const float* be1    = (const float*)d_in[13];
  const float* We2    = (const float*)d_in[14];
  const float* be2    = (const float*)d_in[15];
  const float* Wq     = (const float*)d_in[16];
  const float* Wk     = (const float*)d_in[17];
  const float* eq_nw  = (const float*)d_in[18];
  const float* env_nw = (const float*)d_in[19];
  const float* env_lw = (const float*)d_in[20];
  const float* tp_nw  = (const float*)d_in[21];
  const float* lin_vw = (const float*)d_in[22];
  const int*   ctr    = (const int*)d_in[23];
  const int*   nbr    = (const int*)d_in[24];

  float* out = (float*)d_out;
  float* ws  = (float*)d_ws;
  ushort* Hhi   = (ushort*)(ws + WS_HHI);
  ushort* Hlo   = (ushort*)(ws + WS_HLO);
  float* att    = ws + WS_ATT;
  float* env2   = ws + WS_ENV2;
  int* cnt      = (int*)(ws + WS_CNT);
  int* rowptr   = (int*)(ws + WS_ROWPTR);
  int* cursor   = (int*)(ws + WS_CURSOR);
  int* eidx     = (int*)(ws + WS_EIDX);
  ushort* WB    = (ushort*)(ws + WS_WB);

  hipMemsetAsync(cnt, 0, N_NODES*sizeof(int), stream);

  // CSR build
  hist_kernel<<<E_EDGES/256, 256, 0, stream>>>(ctr, cnt);
  scan_kernel<<<1, 256, 0, stream>>>(cnt, rowptr, cursor);
  scatter_kernel<<<E_EDGES/256, 256, 0, stream>>>(ctr, cursor, eidx);

  // weight conversion (transposed, hi/lo planes)
  wconv_kernel<<<192, 256, 0, stream>>>(W1,  WB+WB_W1H,  WB+WB_W1L,  192, 256);
  wconv_kernel<<<256, 256, 0, stream>>>(W2,  WB+WB_W2H,  WB+WB_W2L,  256, 256);
  wconv_kernel<<<256, 256, 0, stream>>>(We1, WB+WB_WE1H, WB+WB_WE1L, 256, 256);
  wconv_kernel<<<160, 256, 0, stream>>>(We2, WB+WB_WE2H, WB+WB_WE2L, 256, 160);
  wconv_kernel<<<384, 256, 0, stream>>>(Wq,  WB+WB_WQH,  WB+WB_WQL,  192, 512);
  wconv_kernel<<<512, 256, 0, stream>>>(Wk,  WB+WB_WKH,  WB+WB_WKL,  256, 512);

  // G1: silu(x @ W1 + b1) -> H hi/lo
  gemm_wide<1,0,2,8,0><<<E_EDGES/128, 256, 0, stream>>>(
      x, nullptr, D_INF, WB+WB_W1H, WB+WB_W1L, 192, b1,
      Hhi, Hlo, 256, nullptr, nullptr, nullptr);
  // G2: H @ W2 + b2, fused LayerNorm+cutoff -> out cols 0..255 (f32)
  gemm_wide<0,3,0,8,1><<<E_EDGES/128, 256, 0, stream>>>(
      Hhi, Hlo, 256, WB+WB_W2H, WB+WB_W2L, 256, b2,
      out, nullptr, OUT_D, ln_g, ln_b, cut);
  // fused QK -> att (no Q/K materialization)
  qk_att_kernel<<<E_EDGES/128, 256, 0, stream>>>(
      out, ninv, einv, ctr, nbr,
      WB+WB_WQH, WB+WB_WQL, WB+WB_WKH, WB+WB_WKL, att);
  // G3: silu(lat @ We1 + be1) -> H hi/lo (reuse)
  gemm_wide<1,0,2,8,0><<<E_EDGES/128, 256, 0, stream>>>(
      out, nullptr, OUT_D, WB+WB_WE1H, WB+WB_WE1L, 256, be1,
      Hhi, Hlo, 256, nullptr, nullptr, nullptr);
  // G4: H @ We2 + be2 -> out cols 256..415 (f32, N=160)
  gemm_wide<0,3,0,5,0><<<E_EDGES/128, 256, 0, stream>>>(
      Hhi, Hlo, 256, WB+WB_WE2H, WB+WB_WE2L, 256, be2,
      out + 256, nullptr, OUT_D, nullptr, nullptr, nullptr);
  // fused per-node softmax + env + norm + mixing
  node_env_kernel<<<N_NODES, 128, 0, stream>>>(att, eidx, rowptr, eattr, out,
                                               env_nw, env_lw, env2);
  // final per-edge tensor product
  edge_final_kernel<<<E_EDGES/8, 256, 0, stream>>>(eqf, env2, ctr, eq_nw, tp_nw, lin_vw, out);
}